// Round 8
// baseline (1113.923 us; speedup 1.0000x reference)
//
#include <hip/hip_runtime.h>
#include <hip/hip_bf16.h>

#define N_NODES 100000
#define N_EDGES 1600000
#define IN_DIM 128
#define HID 512
#define NCLS 64

typedef __attribute__((ext_vector_type(8))) short bf16x8;
typedef __attribute__((ext_vector_type(4))) float f32x4;

#define RB_COUNT 782   // ceil(N/128)
#define RB_PAD 784     // padded to multiple of 8
#define TG_GRID (RB_PAD * 4)

// ---------- helpers ----------
__device__ inline float bf2f(unsigned short b) {
    unsigned int u = ((unsigned int)b) << 16;
    return __builtin_bit_cast(float, u);
}
__device__ inline unsigned short f2bf(float f) {
    unsigned int u = __builtin_bit_cast(unsigned int, f);
    unsigned int lsb = (u >> 16) & 1u;
    u += 0x7fffu + lsb;
    return (unsigned short)(u >> 16);
}
__device__ inline float selu_f(float x) {
    const float scale = 1.0507009873554805f;
    const float alpha = 1.6732632423543772f;
    return x > 0.f ? scale * x : scale * alpha * (__expf(x) - 1.f);
}
__device__ inline void stb(float* p, float v) { *p = v; }
__device__ inline void stb(unsigned short* p, float v) { *p = f2bf(v); }

// global -> LDS async 16B copy. dst wave-uniform; HW writes lane i at dst + i*16.
__device__ inline void gl_lds16(const void* g, void* l) {
    __builtin_amdgcn_global_load_lds((const __attribute__((address_space(1))) void*)g,
                                     (__attribute__((address_space(3))) void*)l, 16, 0, 0);
}

// ---------- x -> bf16 ----------
__global__ __launch_bounds__(256) void k_cast(const float* __restrict__ x,
                                              unsigned short* __restrict__ xb) {
    size_t g = (size_t)blockIdx.x * 256 + threadIdx.x;
    size_t total = (size_t)N_NODES * IN_DIM / 8;
    if (g >= total) return;
    const float4* p = (const float4*)(x + g * 8);
    float4 v0 = p[0], v1 = p[1];
    uint4 o;
    o.x = (unsigned)f2bf(v0.x) | ((unsigned)f2bf(v0.y) << 16);
    o.y = (unsigned)f2bf(v0.z) | ((unsigned)f2bf(v0.w) << 16);
    o.z = (unsigned)f2bf(v1.x) | ((unsigned)f2bf(v1.y) << 16);
    o.w = (unsigned)f2bf(v1.z) | ((unsigned)f2bf(v1.w) << 16);
    ((uint4*)xb)[g] = o;
}

// ---------- CSR build ----------
__global__ __launch_bounds__(256) void k_deg(const int* __restrict__ dst, int* __restrict__ deg) {
    int e = blockIdx.x * 256 + threadIdx.x;
    if (e < N_EDGES) atomicAdd(&deg[dst[e]], 1);
}

#define SCAN_NB 98  // ceil(100000/1024)

__global__ __launch_bounds__(256) void k_scan_part(const int* __restrict__ deg, int* __restrict__ part) {
    __shared__ int sd[256];
    int b = blockIdx.x, t = threadIdx.x;
    int i0 = b * 1024 + t * 4;
    int s = 0;
#pragma unroll
    for (int k = 0; k < 4; ++k) if (i0 + k < N_NODES) s += deg[i0 + k];
    sd[t] = s;
    __syncthreads();
    for (int o = 128; o > 0; o >>= 1) {
        if (t < o) sd[t] += sd[t + o];
        __syncthreads();
    }
    if (t == 0) part[b] = sd[0];
}

__global__ __launch_bounds__(128) void k_scan_mid(const int* __restrict__ part, int* __restrict__ base,
                                                  int* __restrict__ off) {
    __shared__ int sp[128];
    int t = threadIdx.x;
    int v = (t < SCAN_NB) ? part[t] : 0;
    sp[t] = v;
    __syncthreads();
    for (int o = 1; o < 128; o <<= 1) {
        int tv = (t >= o) ? sp[t - o] : 0;
        __syncthreads();
        sp[t] += tv;
        __syncthreads();
    }
    if (t < SCAN_NB) base[t] = sp[t] - v;
    if (t == SCAN_NB - 1) off[N_NODES] = sp[t];
}

__global__ __launch_bounds__(256) void k_scan_fin(const int* __restrict__ deg, const int* __restrict__ base,
                                                  int* __restrict__ off, int* __restrict__ pos) {
    __shared__ int sd[256];
    int b = blockIdx.x, t = threadIdx.x;
    int i0 = b * 1024 + t * 4;
    int v[4]; int s = 0;
#pragma unroll
    for (int k = 0; k < 4; ++k) { v[k] = (i0 + k < N_NODES) ? deg[i0 + k] : 0; s += v[k]; }
    sd[t] = s;
    __syncthreads();
    for (int o = 1; o < 256; o <<= 1) {
        int tv = (t >= o) ? sd[t - o] : 0;
        __syncthreads();
        sd[t] += tv;
        __syncthreads();
    }
    int excl = base[b] + sd[t] - s;
#pragma unroll
    for (int k = 0; k < 4; ++k) {
        if (i0 + k < N_NODES) { off[i0 + k] = excl; pos[i0 + k] = excl; excl += v[k]; }
    }
}

__global__ __launch_bounds__(256) void k_fill(const int* __restrict__ src, const int* __restrict__ dst,
                                              int* __restrict__ pos, int* __restrict__ adj) {
    int e = blockIdx.x * 256 + threadIdx.x;
    if (e < N_EDGES) {
        int p = atomicAdd(&pos[dst[e]], 1);
        adj[p] = src[e];
    }
}

// ---------- sort each adjacency list by src id (banded temporal locality) ----------
__global__ __launch_bounds__(256) void k_sortadj(const int* __restrict__ off, int* __restrict__ adj) {
    __shared__ int sb[64 * 256];
    int n = blockIdx.x * 256 + threadIdx.x;
    if (n >= N_NODES) return;
    int t = threadIdx.x;
    int e0 = off[n], e1 = off[n + 1];
    int d = e1 - e0;
    if (d <= 1 || d > 64) return;
    for (int i = 0; i < d; ++i) sb[i * 256 + t] = adj[e0 + i];
    for (int i = 1; i < d; ++i) {
        int key = sb[i * 256 + t];
        int j = i - 1;
        while (j >= 0 && sb[j * 256 + t] > key) {
            sb[(j + 1) * 256 + t] = sb[j * 256 + t];
            --j;
        }
        sb[(j + 1) * 256 + t] = key;
    }
    for (int i = 0; i < d; ++i) adj[e0 + i] = sb[i * 256 + t];
}

// ---------- weight packs ----------
__global__ __launch_bounds__(256) void k_pack(const float* __restrict__ W,
                                              unsigned short* __restrict__ Wp, int K, int NC) {
    int idx = blockIdx.x * 256 + threadIdx.x;
    if (idx >= K * NC) return;
    int j = idx & 7;
    int l = (idx >> 3) & 63;
    int t = idx >> 9;
    int KT = K >> 5;
    int kt = t % KT;
    int nt = t / KT;
    int k = kt * 32 + (l >> 4) * 8 + j;
    int n = nt * 16 + (l & 15);
    Wp[idx] = f2bf(W[(size_t)k * NC + n]);
}

__global__ __launch_bounds__(256) void k_packT(const float* __restrict__ W,
                                               unsigned short* __restrict__ WT, int K, int NC) {
    int idx = blockIdx.x * 256 + threadIdx.x;
    if (idx >= K * NC) return;
    int k = idx & (K - 1);
    int n = idx / K;
    WT[idx] = f2bf(W[(size_t)k * NC + n]);
}

// ---------- aggregation layer 1 ----------
__global__ __launch_bounds__(256) void k_agg1(const unsigned short* __restrict__ xb,
                                              const int* __restrict__ off, const int* __restrict__ adj,
                                              unsigned short* __restrict__ A1) {
    int w = (blockIdx.x * 256 + threadIdx.x) >> 6;
    if (w >= N_NODES) return;
    int lane = threadIdx.x & 63;
    unsigned v = ((const unsigned*)(xb + (size_t)w * IN_DIM))[lane];
    float s0 = bf2f((unsigned short)(v & 0xffff));
    float s1 = bf2f((unsigned short)(v >> 16));
    int e0 = off[w], e1 = off[w + 1];
    int e = e0;
    for (; e + 4 <= e1; e += 4) {
        int j0 = adj[e], j1 = adj[e + 1], j2 = adj[e + 2], j3 = adj[e + 3];
        unsigned u0 = ((const unsigned*)(xb + (size_t)j0 * IN_DIM))[lane];
        unsigned u1 = ((const unsigned*)(xb + (size_t)j1 * IN_DIM))[lane];
        unsigned u2 = ((const unsigned*)(xb + (size_t)j2 * IN_DIM))[lane];
        unsigned u3 = ((const unsigned*)(xb + (size_t)j3 * IN_DIM))[lane];
        s0 += bf2f((unsigned short)(u0 & 0xffff)) + bf2f((unsigned short)(u1 & 0xffff)) +
              bf2f((unsigned short)(u2 & 0xffff)) + bf2f((unsigned short)(u3 & 0xffff));
        s1 += bf2f((unsigned short)(u0 >> 16)) + bf2f((unsigned short)(u1 >> 16)) +
              bf2f((unsigned short)(u2 >> 16)) + bf2f((unsigned short)(u3 >> 16));
    }
    for (; e < e1; ++e) {
        unsigned u = ((const unsigned*)(xb + (size_t)adj[e] * IN_DIM))[lane];
        s0 += bf2f((unsigned short)(u & 0xffff));
        s1 += bf2f((unsigned short)(u >> 16));
    }
    ((unsigned*)(A1 + (size_t)w * IN_DIM))[lane] = (unsigned)f2bf(s0) | ((unsigned)f2bf(s1) << 16);
}

// ---------- aggregation layer 2: 64-feature slice, BN1 fused, L2-banded ----------
// One dispatch per slice (sequential) so the instantaneous gather band (~3MB) fits per-XCD L2.
// Wave = node; lane = 16*es + fl: edge-slot es (4 edges in flight) x feature-quad fl (8B).
__global__ __launch_bounds__(256) void k_aggbn8(const unsigned short* __restrict__ h,
                                                const int* __restrict__ off, const int* __restrict__ adj,
                                                const float* __restrict__ bn,
                                                unsigned short* __restrict__ outb, int slice) {
    int w = (blockIdx.x * 256 + threadIdx.x) >> 6;
    if (w >= N_NODES) return;
    int lane = threadIdx.x & 63;
    int es = lane >> 4;
    int fl = lane & 15;
    int fb = slice * 64 + fl * 4;
    const unsigned short* hp = h + fb;
    float s0 = 0.f, s1 = 0.f, s2 = 0.f, s3 = 0.f;
    if (es == 0) {
        // self row: streaming, nontemporal (don't pollute the gather band)
        unsigned long long sv = __builtin_nontemporal_load(
            (const unsigned long long*)(hp + (size_t)w * HID));
        s0 = bf2f((unsigned short)(sv & 0xffff));
        s1 = bf2f((unsigned short)((sv >> 16) & 0xffff));
        s2 = bf2f((unsigned short)((sv >> 32) & 0xffff));
        s3 = bf2f((unsigned short)((sv >> 48) & 0xffff));
    }
    int e0 = off[w], e1 = off[w + 1];
    int e = e0 + es;
    // 2-deep unrolled: 8 edges in flight per wave
    for (; e + 4 < e1; e += 8) {
        int ja = adj[e], jb = adj[e + 4];
        uint2 ua = *(const uint2*)(hp + (size_t)ja * HID);
        uint2 ub = *(const uint2*)(hp + (size_t)jb * HID);
        s0 += bf2f((unsigned short)(ua.x & 0xffff)) + bf2f((unsigned short)(ub.x & 0xffff));
        s1 += bf2f((unsigned short)(ua.x >> 16)) + bf2f((unsigned short)(ub.x >> 16));
        s2 += bf2f((unsigned short)(ua.y & 0xffff)) + bf2f((unsigned short)(ub.y & 0xffff));
        s3 += bf2f((unsigned short)(ua.y >> 16)) + bf2f((unsigned short)(ub.y >> 16));
    }
    for (; e < e1; e += 4) {
        int j = adj[e];
        uint2 u = *(const uint2*)(hp + (size_t)j * HID);
        s0 += bf2f((unsigned short)(u.x & 0xffff));
        s1 += bf2f((unsigned short)(u.x >> 16));
        s2 += bf2f((unsigned short)(u.y & 0xffff));
        s3 += bf2f((unsigned short)(u.y >> 16));
    }
    // reduce the 4 edge-slots
    s0 += __shfl_xor(s0, 16); s0 += __shfl_xor(s0, 32);
    s1 += __shfl_xor(s1, 16); s1 += __shfl_xor(s1, 32);
    s2 += __shfl_xor(s2, 16); s2 += __shfl_xor(s2, 32);
    s3 += __shfl_xor(s3, 16); s3 += __shfl_xor(s3, 32);
    if (es == 0) {
        float dp1 = (float)(e1 - e0 + 1);
        float r0 = s0 * bn[2 * HID + fb + 0] + dp1 * bn[3 * HID + fb + 0];
        float r1 = s1 * bn[2 * HID + fb + 1] + dp1 * bn[3 * HID + fb + 1];
        float r2 = s2 * bn[2 * HID + fb + 2] + dp1 * bn[3 * HID + fb + 2];
        float r3 = s3 * bn[2 * HID + fb + 3] + dp1 * bn[3 * HID + fb + 3];
        unsigned long long o =
            (unsigned long long)((unsigned)f2bf(r0) | ((unsigned)f2bf(r1) << 16)) |
            ((unsigned long long)((unsigned)f2bf(r2) | ((unsigned)f2bf(r3) << 16)) << 32);
        __builtin_nontemporal_store(o, (unsigned long long*)(outb + (size_t)w * HID + fb));
    }
}

// ---------- LDS-staged MFMA GEMM with XCD-grouped block mapping ----------
template <int K, int ACT, int STATS>
__global__ __launch_bounds__(256) void k_tgemm(const unsigned short* __restrict__ A,
                                               const unsigned short* __restrict__ WT,
                                               const float* __restrict__ bias,
                                               unsigned short* __restrict__ Out,
                                               float* __restrict__ scratch, int M) {
    constexpr int NC = 512;
    __shared__ __align__(16) char smem[32768 + 2048];
    const int bid = blockIdx.x;
    const int r8 = bid & 7;
    const int q = bid >> 3;
    const int cb = q & 3;
    const int rb = (q >> 2) * 8 + r8;
    const int rowbase = rb * 128;
    const int colbase = cb * 128;
    if (rowbase >= M) return;

    const int tid = threadIdx.x;
    const int lane = tid & 63;
    const int w = tid >> 6;
    const int wm = w >> 1, wn = w & 1;
    const int l15 = lane & 15, lg = lane >> 4;

    f32x4 acc[4][4];
#pragma unroll
    for (int i = 0; i < 4; ++i)
#pragma unroll
        for (int j = 0; j < 4; ++j) acc[i][j] = (f32x4)0.f;

    for (int k0 = 0; k0 < K; k0 += 64) {
#pragma unroll
        for (int i = 0; i < 4; ++i) {
            int slot = i * 256 + tid;
            int r = slot >> 3;
            int u = (slot & 7) ^ (r & 7);
            int gr = rowbase + r; if (gr >= M) gr = M - 1;
            gl_lds16(A + (size_t)gr * K + k0 + u * 8, smem + (i * 256 + w * 64) * 16);
        }
#pragma unroll
        for (int i = 0; i < 4; ++i) {
            int slot = i * 256 + tid;
            int c = slot >> 3;
            int u = (slot & 7) ^ (c & 7);
            gl_lds16(WT + (size_t)(colbase + c) * K + k0 + u * 8,
                     smem + 16384 + (i * 256 + w * 64) * 16);
        }
        __syncthreads();
#pragma unroll
        for (int kin = 0; kin < 2; ++kin) {
            bf16x8 af[4], bfr[4];
#pragma unroll
            for (int mi = 0; mi < 4; ++mi) {
                int r = wm * 64 + mi * 16 + l15;
                int u = (kin * 4 + lg) ^ (r & 7);
                af[mi] = *(const bf16x8*)(smem + r * 128 + u * 16);
            }
#pragma unroll
            for (int ni = 0; ni < 4; ++ni) {
                int c = wn * 64 + ni * 16 + l15;
                int u = (kin * 4 + lg) ^ (c & 7);
                bfr[ni] = *(const bf16x8*)(smem + 16384 + c * 128 + u * 16);
            }
#pragma unroll
            for (int mi = 0; mi < 4; ++mi)
#pragma unroll
                for (int ni = 0; ni < 4; ++ni)
                    acc[mi][ni] = __builtin_amdgcn_mfma_f32_16x16x32_bf16(af[mi], bfr[ni], acc[mi][ni], 0, 0, 0);
        }
        __syncthreads();
    }

    float cs[4], cq[4];
    if (STATS) {
#pragma unroll
        for (int ni = 0; ni < 4; ++ni) { cs[ni] = 0.f; cq[ni] = 0.f; }
    }
#pragma unroll
    for (int ni = 0; ni < 4; ++ni) {
        int c = wn * 64 + ni * 16 + l15;
        float bv = bias[colbase + c];
#pragma unroll
        for (int mi = 0; mi < 4; ++mi) {
#pragma unroll
            for (int r = 0; r < 4; ++r) {
                int row = wm * 64 + mi * 16 + lg * 4 + r;
                float t = acc[mi][ni][r] + bv;
                t = (ACT == 0) ? fmaxf(t, 0.f) : selu_f(t);
                if (STATS && (rowbase + row < M)) { cs[ni] += t; cq[ni] += t * t; }
                int byte = (row * 256 + c * 2) ^ ((row & 7) << 4);
                *(unsigned short*)(smem + byte) = f2bf(t);
            }
        }
    }
    if (STATS) {
        float* sS = (float*)(smem + 32768);
#pragma unroll
        for (int ni = 0; ni < 4; ++ni) {
            float a = cs[ni];
            a += __shfl_xor(a, 16); a += __shfl_xor(a, 32);
            float b = cq[ni];
            b += __shfl_xor(b, 16); b += __shfl_xor(b, 32);
            if (lg == 0) {
                sS[wm * 256 + (wn * 64 + ni * 16 + l15)] = a;
                sS[wm * 256 + 128 + (wn * 64 + ni * 16 + l15)] = b;
            }
        }
    }
    __syncthreads();
#pragma unroll
    for (int it = 0; it < 8; ++it) {
        int idx = it * 256 + tid;
        int row = idx >> 4;
        int ch = idx & 15;
        int gr = rowbase + row;
        if (gr < M) {
            uint4 v = *(const uint4*)(smem + row * 256 + ((ch ^ (row & 7)) << 4));
            *(uint4*)(Out + (size_t)gr * NC + colbase + ch * 8) = v;
        }
    }
    if (STATS) {
        const float* sS = (const float*)(smem + 32768);
        int c = tid & 127, kind = tid >> 7;
        float v = sS[kind * 128 + c] + sS[256 + kind * 128 + c];
        scratch[(size_t)(rb * 4 + cb) * 256 + kind * 128 + c] = v;
    }
}

// ---------- BN1 partial reduce ----------
__global__ __launch_bounds__(256) void k_bnred(const float* __restrict__ scratch,
                                               float* __restrict__ bn) {
    int t = threadIdx.x;
    float loc[4] = {0.f, 0.f, 0.f, 0.f};
    for (int rb = blockIdx.x; rb < RB_COUNT; rb += gridDim.x) {
#pragma unroll
        for (int cbk = 0; cbk < 4; ++cbk)
            loc[cbk] += scratch[(size_t)(rb * 4 + cbk) * 256 + t];
    }
    int kind = t >> 7, cl = t & 127;
#pragma unroll
    for (int cbk = 0; cbk < 4; ++cbk)
        atomicAdd(&bn[kind * HID + cbk * 128 + cl], loc[cbk]);
}

// ---------- register-direct MFMA GEMM (final small GEMM, f32 out, fused BN2 stats) ----------
template <int K, int NC, int ACT, int WAVES_M, int WAVES_N, int NFRAG, int STATS, typename TOUT>
__global__ __launch_bounds__(WAVES_M * WAVES_N * 64) void k_mgemm(
    const unsigned short* __restrict__ A, const unsigned short* __restrict__ Wp,
    const float* __restrict__ bias, TOUT* __restrict__ Out, float* __restrict__ bnacc, int M) {
    __shared__ float sS[WAVES_M * WAVES_N * 128];
    const int tid = threadIdx.x;
    const int lane = tid & 63;
    const int w = tid >> 6;
    const int wm = w / WAVES_N;
    const int wn = w % WAVES_N;
    const int l15 = lane & 15;
    const int lg = lane >> 4;
    const int rowbase = blockIdx.x * (32 * WAVES_M) + wm * 32;
    const int colbase = blockIdx.y * (WAVES_N * 16 * NFRAG) + wn * 16 * NFRAG;
    int r0 = rowbase + l15; if (r0 > M - 1) r0 = M - 1;
    int r1 = rowbase + 16 + l15; if (r1 > M - 1) r1 = M - 1;
    const unsigned short* pa0 = A + (size_t)r0 * K + lg * 8;
    const unsigned short* pa1 = A + (size_t)r1 * K + lg * 8;
    const unsigned short* pw = Wp + (size_t)(colbase >> 4) * (K / 32) * 512 + lane * 8;

    f32x4 acc[2][NFRAG];
#pragma unroll
    for (int i = 0; i < 2; ++i)
#pragma unroll
        for (int j = 0; j < NFRAG; ++j) acc[i][j] = (f32x4)0.f;

#pragma unroll 2
    for (int kt = 0; kt < K / 32; ++kt) {
        bf16x8 a0 = *(const bf16x8*)(pa0 + kt * 32);
        bf16x8 a1 = *(const bf16x8*)(pa1 + kt * 32);
#pragma unroll
        for (int ni = 0; ni < NFRAG; ++ni) {
            bf16x8 bv = *(const bf16x8*)(pw + (ni * (K / 32) + kt) * 512);
            acc[0][ni] = __builtin_amdgcn_mfma_f32_16x16x32_bf16(a0, bv, acc[0][ni], 0, 0, 0);
            acc[1][ni] = __builtin_amdgcn_mfma_f32_16x16x32_bf16(a1, bv, acc[1][ni], 0, 0, 0);
        }
    }

    float cs[NFRAG], cq[NFRAG];
    if (STATS) {
#pragma unroll
        for (int ni = 0; ni < NFRAG; ++ni) { cs[ni] = 0.f; cq[ni] = 0.f; }
    }
#pragma unroll
    for (int ni = 0; ni < NFRAG; ++ni) {
        int c = colbase + ni * 16 + l15;
        float bv = bias[c];
#pragma unroll
        for (int mi = 0; mi < 2; ++mi) {
#pragma unroll
            for (int r = 0; r < 4; ++r) {
                int row = rowbase + mi * 16 + lg * 4 + r;
                if (row < M) {
                    float t = acc[mi][ni][r] + bv;
                    t = (ACT == 0) ? fmaxf(t, 0.f) : selu_f(t);
                    if (STATS) { cs[ni] += t; cq[ni] += t * t; }
                    stb(&Out[(size_t)row * NC + c], t);
                }
            }
        }
    }
    if (STATS) {
#pragma unroll
        for (int ni = 0; ni < NFRAG; ++ni) {
            float a = cs[ni];
            a += __shfl_xor(a, 16); a += __shfl_xor(a, 32);
            float b = cq[ni];
            b += __shfl_xor(b, 16); b += __shfl_xor(b, 32);
            if (lg == 0) {
                sS[w * 128 + (ni * 16 + l15)] = a;
                sS[w * 128 + 64 + (ni * 16 + l15)] = b;
            }
        }
        __syncthreads();
        if (tid < 128) {
            float v = 0.f;
#pragma unroll
            for (int ww = 0; ww < WAVES_M * WAVES_N; ++ww) v += sS[ww * 128 + tid];
            atomicAdd(&bnacc[tid], v);
        }
    }
}

// ---------- BN prep / softmax ----------
__global__ void k_bnprep(float* __restrict__ bn, const float* __restrict__ gamma,
                         const float* __restrict__ beta, int C, float invn) {
    int c = threadIdx.x + blockIdx.x * blockDim.x;
    if (c >= C) return;
    float mu = bn[c] * invn;
    float var = bn[C + c] * invn - mu * mu;
    float sc = gamma[c] * rsqrtf(var + 1e-5f);
    bn[2 * C + c] = sc;
    bn[3 * C + c] = beta[c] - mu * sc;
}

__global__ __launch_bounds__(256) void k_softmax(float* __restrict__ O, const float* __restrict__ bn2) {
    int w = (blockIdx.x * 256 + threadIdx.x) >> 6;
    if (w >= N_NODES) return;
    int lane = threadIdx.x & 63;
    float z = O[(size_t)w * NCLS + lane] * bn2[2 * NCLS + lane] + bn2[3 * NCLS + lane];
    float m = z;
#pragma unroll
    for (int o = 32; o > 0; o >>= 1) m = fmaxf(m, __shfl_xor(m, o));
    float e = __expf(z - m);
    float s = e;
#pragma unroll
    for (int o = 32; o > 0; o >>= 1) s += __shfl_xor(s, o);
    O[(size_t)w * NCLS + lane] = e / s;
}

// ---------- launch ----------
extern "C" void kernel_launch(void* const* d_in, const int* in_sizes, int n_in,
                              void* d_out, int out_size, void* d_ws, size_t ws_size,
                              hipStream_t stream) {
    const float* x = (const float*)d_in[0];
    const int* edge = (const int*)d_in[1];
    const int* srcp = edge;
    const int* dstp = edge + N_EDGES;
    const float* W1a = (const float*)d_in[9];
    const float* b1a = (const float*)d_in[10];
    const float* W1b = (const float*)d_in[11];
    const float* b1b = (const float*)d_in[12];
    const float* gamma1 = (const float*)d_in[13];
    const float* beta1 = (const float*)d_in[14];
    const float* W2a = (const float*)d_in[15];
    const float* b2a = (const float*)d_in[16];
    const float* W2b = (const float*)d_in[17];
    const float* b2b = (const float*)d_in[18];
    const float* gamma2 = (const float*)d_in[19];
    const float* beta2 = (const float*)d_in[20];
    float* out = (float*)d_out;

    char* ws = (char*)d_ws;
    size_t o = 0;
    auto alloc = [&](size_t bytes) -> char* {
        char* p = ws + o;
        o = (o + bytes + 255) & ~(size_t)255;
        return p;
    };
    int* off = (int*)alloc((N_NODES + 1) * sizeof(int));
    int* deg = (int*)alloc(N_NODES * sizeof(int));
    int* pos = (int*)alloc(N_NODES * sizeof(int));
    int* adj = (int*)alloc(N_EDGES * sizeof(int));
    int* part = (int*)alloc(SCAN_NB * sizeof(int));
    int* base = (int*)alloc(SCAN_NB * sizeof(int));
    float* bn1 = (float*)alloc(4 * HID * sizeof(float));
    float* bn2 = (float*)alloc(4 * NCLS * sizeof(float));
    float* stat = (float*)alloc((size_t)RB_COUNT * 4 * 256 * sizeof(float));
    unsigned short* WT1 = (unsigned short*)alloc((size_t)IN_DIM * HID * sizeof(unsigned short));
    unsigned short* WT2 = (unsigned short*)alloc((size_t)HID * HID * sizeof(unsigned short));
    unsigned short* WT3 = (unsigned short*)alloc((size_t)HID * HID * sizeof(unsigned short));
    unsigned short* Wp4 = (unsigned short*)alloc((size_t)HID * NCLS * sizeof(unsigned short));
    unsigned short* xb = (unsigned short*)alloc((size_t)N_NODES * IN_DIM * sizeof(unsigned short));
    unsigned short* A1 = (unsigned short*)alloc((size_t)N_NODES * IN_DIM * sizeof(unsigned short));
    unsigned short* B = (unsigned short*)alloc((size_t)N_NODES * HID * sizeof(unsigned short));
    unsigned short* C = (unsigned short*)alloc((size_t)N_NODES * HID * sizeof(unsigned short));

    hipMemsetAsync(deg, 0, N_NODES * sizeof(int), stream);
    hipMemsetAsync(bn1, 0, 2 * HID * sizeof(float), stream);
    hipMemsetAsync(bn2, 0, 2 * NCLS * sizeof(float), stream);

    int eb = (N_EDGES + 255) / 256;
    k_cast<<<(N_NODES * IN_DIM / 8 + 255) / 256, 256, 0, stream>>>(x, xb);
    k_deg<<<eb, 256, 0, stream>>>(dstp, deg);
    k_scan_part<<<SCAN_NB, 256, 0, stream>>>(deg, part);
    k_scan_mid<<<1, 128, 0, stream>>>(part, base, off);
    k_scan_fin<<<SCAN_NB, 256, 0, stream>>>(deg, base, off, pos);
    k_fill<<<eb, 256, 0, stream>>>(srcp, dstp, pos, adj);
    k_sortadj<<<(N_NODES + 255) / 256, 256, 0, stream>>>(off, adj);

    k_packT<<<(IN_DIM * HID) / 256, 256, 0, stream>>>(W1a, WT1, IN_DIM, HID);
    k_packT<<<(HID * HID) / 256, 256, 0, stream>>>(W1b, WT2, HID, HID);
    k_packT<<<(HID * HID) / 256, 256, 0, stream>>>(W2a, WT3, HID, HID);
    k_pack<<<(HID * NCLS) / 256, 256, 0, stream>>>(W2b, Wp4, HID, NCLS);

    int nwb = (N_NODES * 64 + 255) / 256;  // one wave per node

    // layer 1
    k_agg1<<<nwb, 256, 0, stream>>>(xb, off, adj, A1);
    k_tgemm<IN_DIM, 0, 0><<<TG_GRID, 256, 0, stream>>>(A1, WT1, b1a, B, nullptr, N_NODES);
    k_tgemm<HID, 1, 1><<<TG_GRID, 256, 0, stream>>>(B, WT2, b1b, C, stat, N_NODES);
    k_bnred<<<32, 256, 0, stream>>>(stat, bn1);
    k_bnprep<<<2, 256, 0, stream>>>(bn1, gamma1, beta1, HID, 1.0f / N_NODES);

    // layer 2: 8 sequential 64-feature gather slices (L2-banded)
    for (int sl = 0; sl < 8; ++sl)
        k_aggbn8<<<nwb, 256, 0, stream>>>(C, off, adj, bn1, B, sl);

    k_tgemm<HID, 0, 0><<<TG_GRID, 256, 0, stream>>>(B, WT3, b2a, C, N_NODES ? nullptr : nullptr, N_NODES);
    k_mgemm<HID, NCLS, 1, 8, 1, 4, 1, float><<<dim3((N_NODES + 255) / 256, 1), 512, 0, stream>>>(C, Wp4, b2b, out, bn2, N_NODES);

    k_bnprep<<<1, 64, 0, stream>>>(bn2, gamma2, beta2, NCLS, 1.0f / N_NODES);
    k_softmax<<<nwb, 256, 0, stream>>>(out, bn2);
}

// Round 9
// 949.421 us; speedup vs baseline: 1.1733x; 1.1733x over previous
//
#include <hip/hip_runtime.h>
#include <hip/hip_bf16.h>

#define N_NODES 100000
#define N_EDGES 1600000
#define IN_DIM 128
#define HID 512
#define NCLS 64

typedef __attribute__((ext_vector_type(8))) short bf16x8;
typedef __attribute__((ext_vector_type(4))) float f32x4;

#define RB_COUNT 782   // ceil(N/128)
#define RB_PAD 784     // padded to multiple of 8
#define TG_GRID (RB_PAD * 4)

// ---------- helpers ----------
__device__ inline float bf2f(unsigned short b) {
    unsigned int u = ((unsigned int)b) << 16;
    return __builtin_bit_cast(float, u);
}
__device__ inline unsigned short f2bf(float f) {
    unsigned int u = __builtin_bit_cast(unsigned int, f);
    unsigned int lsb = (u >> 16) & 1u;
    u += 0x7fffu + lsb;
    return (unsigned short)(u >> 16);
}
__device__ inline float selu_f(float x) {
    const float scale = 1.0507009873554805f;
    const float alpha = 1.6732632423543772f;
    return x > 0.f ? scale * x : scale * alpha * (__expf(x) - 1.f);
}
__device__ inline void stb(float* p, float v) { *p = v; }
__device__ inline void stb(unsigned short* p, float v) { *p = f2bf(v); }

// global -> LDS async 16B copy. dst wave-uniform; HW writes lane i at dst + i*16.
__device__ inline void gl_lds16(const void* g, void* l) {
    __builtin_amdgcn_global_load_lds((const __attribute__((address_space(1))) void*)g,
                                     (__attribute__((address_space(3))) void*)l, 16, 0, 0);
}

// ---------- x -> bf16 ----------
__global__ __launch_bounds__(256) void k_cast(const float* __restrict__ x,
                                              unsigned short* __restrict__ xb) {
    size_t g = (size_t)blockIdx.x * 256 + threadIdx.x;
    size_t total = (size_t)N_NODES * IN_DIM / 8;
    if (g >= total) return;
    const float4* p = (const float4*)(x + g * 8);
    float4 v0 = p[0], v1 = p[1];
    uint4 o;
    o.x = (unsigned)f2bf(v0.x) | ((unsigned)f2bf(v0.y) << 16);
    o.y = (unsigned)f2bf(v0.z) | ((unsigned)f2bf(v0.w) << 16);
    o.z = (unsigned)f2bf(v1.x) | ((unsigned)f2bf(v1.y) << 16);
    o.w = (unsigned)f2bf(v1.z) | ((unsigned)f2bf(v1.w) << 16);
    ((uint4*)xb)[g] = o;
}

// ---------- CSR build ----------
__global__ __launch_bounds__(256) void k_deg(const int* __restrict__ dst, int* __restrict__ deg) {
    int e = blockIdx.x * 256 + threadIdx.x;
    if (e < N_EDGES) atomicAdd(&deg[dst[e]], 1);
}

#define SCAN_NB 98  // ceil(100000/1024)

__global__ __launch_bounds__(256) void k_scan_part(const int* __restrict__ deg, int* __restrict__ part) {
    __shared__ int sd[256];
    int b = blockIdx.x, t = threadIdx.x;
    int i0 = b * 1024 + t * 4;
    int s = 0;
#pragma unroll
    for (int k = 0; k < 4; ++k) if (i0 + k < N_NODES) s += deg[i0 + k];
    sd[t] = s;
    __syncthreads();
    for (int o = 128; o > 0; o >>= 1) {
        if (t < o) sd[t] += sd[t + o];
        __syncthreads();
    }
    if (t == 0) part[b] = sd[0];
}

__global__ __launch_bounds__(128) void k_scan_mid(const int* __restrict__ part, int* __restrict__ base,
                                                  int* __restrict__ off) {
    __shared__ int sp[128];
    int t = threadIdx.x;
    int v = (t < SCAN_NB) ? part[t] : 0;
    sp[t] = v;
    __syncthreads();
    for (int o = 1; o < 128; o <<= 1) {
        int tv = (t >= o) ? sp[t - o] : 0;
        __syncthreads();
        sp[t] += tv;
        __syncthreads();
    }
    if (t < SCAN_NB) base[t] = sp[t] - v;
    if (t == SCAN_NB - 1) off[N_NODES] = sp[t];
}

__global__ __launch_bounds__(256) void k_scan_fin(const int* __restrict__ deg, const int* __restrict__ base,
                                                  int* __restrict__ off, int* __restrict__ pos) {
    __shared__ int sd[256];
    int b = blockIdx.x, t = threadIdx.x;
    int i0 = b * 1024 + t * 4;
    int v[4]; int s = 0;
#pragma unroll
    for (int k = 0; k < 4; ++k) { v[k] = (i0 + k < N_NODES) ? deg[i0 + k] : 0; s += v[k]; }
    sd[t] = s;
    __syncthreads();
    for (int o = 1; o < 256; o <<= 1) {
        int tv = (t >= o) ? sd[t - o] : 0;
        __syncthreads();
        sd[t] += tv;
        __syncthreads();
    }
    int excl = base[b] + sd[t] - s;
#pragma unroll
    for (int k = 0; k < 4; ++k) {
        if (i0 + k < N_NODES) { off[i0 + k] = excl; pos[i0 + k] = excl; excl += v[k]; }
    }
}

__global__ __launch_bounds__(256) void k_fill(const int* __restrict__ src, const int* __restrict__ dst,
                                              int* __restrict__ pos, int* __restrict__ adj) {
    int e = blockIdx.x * 256 + threadIdx.x;
    if (e < N_EDGES) {
        int p = atomicAdd(&pos[dst[e]], 1);
        adj[p] = src[e];
    }
}

// ---------- sort each adjacency list by src id (banded temporal locality) ----------
__global__ __launch_bounds__(256) void k_sortadj(const int* __restrict__ off, int* __restrict__ adj) {
    __shared__ int sb[64 * 256];
    int n = blockIdx.x * 256 + threadIdx.x;
    if (n >= N_NODES) return;
    int t = threadIdx.x;
    int e0 = off[n], e1 = off[n + 1];
    int d = e1 - e0;
    if (d <= 1 || d > 64) return;
    for (int i = 0; i < d; ++i) sb[i * 256 + t] = adj[e0 + i];
    for (int i = 1; i < d; ++i) {
        int key = sb[i * 256 + t];
        int j = i - 1;
        while (j >= 0 && sb[j * 256 + t] > key) {
            sb[(j + 1) * 256 + t] = sb[j * 256 + t];
            --j;
        }
        sb[(j + 1) * 256 + t] = key;
    }
    for (int i = 0; i < d; ++i) adj[e0 + i] = sb[i * 256 + t];
}

// ---------- weight pack (fragment-ready bf16) ----------
// Wp[((nt*(K/32)+kt)*64 + lane)*8 + j] = bf16(W[kt*32 + (lane>>4)*8 + j][nt*16 + (lane&15)])
__global__ __launch_bounds__(256) void k_pack(const float* __restrict__ W,
                                              unsigned short* __restrict__ Wp, int K, int NC) {
    int idx = blockIdx.x * 256 + threadIdx.x;
    if (idx >= K * NC) return;
    int j = idx & 7;
    int l = (idx >> 3) & 63;
    int t = idx >> 9;
    int KT = K >> 5;
    int kt = t % KT;
    int nt = t / KT;
    int k = kt * 32 + (l >> 4) * 8 + j;
    int n = nt * 16 + (l & 15);
    Wp[idx] = f2bf(W[(size_t)k * NC + n]);
}

// ---------- aggregation layer 1 ----------
__global__ __launch_bounds__(256) void k_agg1(const unsigned short* __restrict__ xb,
                                              const int* __restrict__ off, const int* __restrict__ adj,
                                              unsigned short* __restrict__ A1) {
    int w = (blockIdx.x * 256 + threadIdx.x) >> 6;
    if (w >= N_NODES) return;
    int lane = threadIdx.x & 63;
    unsigned v = ((const unsigned*)(xb + (size_t)w * IN_DIM))[lane];
    float s0 = bf2f((unsigned short)(v & 0xffff));
    float s1 = bf2f((unsigned short)(v >> 16));
    int e0 = off[w], e1 = off[w + 1];
    int e = e0;
    for (; e + 4 <= e1; e += 4) {
        int j0 = adj[e], j1 = adj[e + 1], j2 = adj[e + 2], j3 = adj[e + 3];
        unsigned u0 = ((const unsigned*)(xb + (size_t)j0 * IN_DIM))[lane];
        unsigned u1 = ((const unsigned*)(xb + (size_t)j1 * IN_DIM))[lane];
        unsigned u2 = ((const unsigned*)(xb + (size_t)j2 * IN_DIM))[lane];
        unsigned u3 = ((const unsigned*)(xb + (size_t)j3 * IN_DIM))[lane];
        s0 += bf2f((unsigned short)(u0 & 0xffff)) + bf2f((unsigned short)(u1 & 0xffff)) +
              bf2f((unsigned short)(u2 & 0xffff)) + bf2f((unsigned short)(u3 & 0xffff));
        s1 += bf2f((unsigned short)(u0 >> 16)) + bf2f((unsigned short)(u1 >> 16)) +
              bf2f((unsigned short)(u2 >> 16)) + bf2f((unsigned short)(u3 >> 16));
    }
    for (; e < e1; ++e) {
        unsigned u = ((const unsigned*)(xb + (size_t)adj[e] * IN_DIM))[lane];
        s0 += bf2f((unsigned short)(u & 0xffff));
        s1 += bf2f((unsigned short)(u >> 16));
    }
    ((unsigned*)(A1 + (size_t)w * IN_DIM))[lane] = (unsigned)f2bf(s0) | ((unsigned)f2bf(s1) << 16);
}

// ---------- aggregation layer 2, feature-sliced, BN1 fused (proven round-7 form) ----------
__global__ __launch_bounds__(256) void k_aggbn2(const unsigned short* __restrict__ h,
                                                const int* __restrict__ off, const int* __restrict__ adj,
                                                const float* __restrict__ bn,
                                                unsigned short* __restrict__ outb) {
    int w = (blockIdx.x * 256 + threadIdx.x) >> 6;
    if (w >= N_NODES) return;
    int lane = threadIdx.x & 63;
    int fb = blockIdx.y * 256 + lane * 4;
    const unsigned short* hp = h + fb;
    float scl[4], shf[4];
#pragma unroll
    for (int k = 0; k < 4; ++k) {
        scl[k] = bn[2 * HID + fb + k];
        shf[k] = bn[3 * HID + fb + k];
    }
    uint2 v = *(const uint2*)(hp + (size_t)w * HID);
    float s0 = bf2f((unsigned short)(v.x & 0xffff));
    float s1 = bf2f((unsigned short)(v.x >> 16));
    float s2 = bf2f((unsigned short)(v.y & 0xffff));
    float s3 = bf2f((unsigned short)(v.y >> 16));
    int e0 = off[w], e1 = off[w + 1];
    int e = e0;
    for (; e + 4 <= e1; e += 4) {
        int j0 = adj[e], j1 = adj[e + 1], j2 = adj[e + 2], j3 = adj[e + 3];
        uint2 u0 = *(const uint2*)(hp + (size_t)j0 * HID);
        uint2 u1 = *(const uint2*)(hp + (size_t)j1 * HID);
        uint2 u2 = *(const uint2*)(hp + (size_t)j2 * HID);
        uint2 u3 = *(const uint2*)(hp + (size_t)j3 * HID);
        s0 += bf2f((unsigned short)(u0.x & 0xffff)) + bf2f((unsigned short)(u1.x & 0xffff)) +
              bf2f((unsigned short)(u2.x & 0xffff)) + bf2f((unsigned short)(u3.x & 0xffff));
        s1 += bf2f((unsigned short)(u0.x >> 16)) + bf2f((unsigned short)(u1.x >> 16)) +
              bf2f((unsigned short)(u2.x >> 16)) + bf2f((unsigned short)(u3.x >> 16));
        s2 += bf2f((unsigned short)(u0.y & 0xffff)) + bf2f((unsigned short)(u1.y & 0xffff)) +
              bf2f((unsigned short)(u2.y & 0xffff)) + bf2f((unsigned short)(u3.y & 0xffff));
        s3 += bf2f((unsigned short)(u0.y >> 16)) + bf2f((unsigned short)(u1.y >> 16)) +
              bf2f((unsigned short)(u2.y >> 16)) + bf2f((unsigned short)(u3.y >> 16));
    }
    for (; e < e1; ++e) {
        uint2 u = *(const uint2*)(hp + (size_t)adj[e] * HID);
        s0 += bf2f((unsigned short)(u.x & 0xffff));
        s1 += bf2f((unsigned short)(u.x >> 16));
        s2 += bf2f((unsigned short)(u.y & 0xffff));
        s3 += bf2f((unsigned short)(u.y >> 16));
    }
    float dp1 = (float)(e1 - e0 + 1);
    float r0 = s0 * scl[0] + dp1 * shf[0];
    float r1 = s1 * scl[1] + dp1 * shf[1];
    float r2 = s2 * scl[2] + dp1 * shf[2];
    float r3 = s3 * scl[3] + dp1 * shf[3];
    unsigned long long o =
        (unsigned long long)((unsigned)f2bf(r0) | ((unsigned)f2bf(r1) << 16)) |
        ((unsigned long long)((unsigned)f2bf(r2) | ((unsigned)f2bf(r3) << 16)) << 32);
    __builtin_nontemporal_store(o, (unsigned long long*)(outb + (size_t)w * HID + fb));
}

// ---------- hybrid MFMA GEMM: LDS-staged A, register-direct B (packed Wp) ----------
// Out[M,512] = act(A[M,K] @ W + bias). Tile 128x128, 4 waves (2M x 2N), per-wave 64x64.
// LDS: 16KB A tile only; epilogue reuses it in two 64-row half-passes.
template <int K, int ACT, int STATS>
__global__ __launch_bounds__(256) void k_hgemm(const unsigned short* __restrict__ A,
                                               const unsigned short* __restrict__ Wp,
                                               const float* __restrict__ bias,
                                               unsigned short* __restrict__ Out,
                                               float* __restrict__ scratch, int M) {
    constexpr int NC = 512;
    constexpr int KT = K / 32;
    __shared__ __align__(16) char smem[16384 + 2048];
    const int bid = blockIdx.x;
    const int r8 = bid & 7;
    const int q = bid >> 3;
    const int cb = q & 3;
    const int rb = (q >> 2) * 8 + r8;
    const int rowbase = rb * 128;
    const int colbase = cb * 128;
    if (rowbase >= M) return;

    const int tid = threadIdx.x;
    const int lane = tid & 63;
    const int w = tid >> 6;
    const int wm = w >> 1, wn = w & 1;
    const int l15 = lane & 15, lg = lane >> 4;
    const int ntbase = (colbase >> 4) + wn * 4;
    const unsigned short* pwb = Wp + (size_t)lane * 8;

    f32x4 acc[4][4];
#pragma unroll
    for (int i = 0; i < 4; ++i)
#pragma unroll
        for (int j = 0; j < 4; ++j) acc[i][j] = (f32x4)0.f;

    for (int k0 = 0; k0 < K; k0 += 64) {
        // stage A tile: 128 rows x 64 k = 16KB, pre-swizzled source (rule 21)
#pragma unroll
        for (int i = 0; i < 4; ++i) {
            int slot = i * 256 + tid;
            int r = slot >> 3;
            int u = (slot & 7) ^ (r & 7);
            int gr = rowbase + r; if (gr >= M) gr = M - 1;
            gl_lds16(A + (size_t)gr * K + k0 + u * 8, smem + (i * 256 + w * 64) * 16);
        }
        __syncthreads();
#pragma unroll
        for (int kin = 0; kin < 2; ++kin) {
            int kt = (k0 >> 5) + kin;
            bf16x8 af[4], bv[4];
#pragma unroll
            for (int mi = 0; mi < 4; ++mi) {
                int r = wm * 64 + mi * 16 + l15;
                int u = (kin * 4 + lg) ^ (r & 7);
                af[mi] = *(const bf16x8*)(smem + r * 128 + u * 16);
            }
#pragma unroll
            for (int ni = 0; ni < 4; ++ni)
                bv[ni] = *(const bf16x8*)(pwb + (size_t)((ntbase + ni) * KT + kt) * 512);
#pragma unroll
            for (int ni = 0; ni < 4; ++ni)
#pragma unroll
                for (int mi = 0; mi < 4; ++mi)
                    acc[mi][ni] = __builtin_amdgcn_mfma_f32_16x16x32_bf16(af[mi], bv[ni], acc[mi][ni], 0, 0, 0);
        }
        __syncthreads();
    }

    // epilogue: bias+act -> two 64-row half-passes through the 16KB LDS buffer
    float cs[4], cq[4];
    if (STATS) {
#pragma unroll
        for (int ni = 0; ni < 4; ++ni) { cs[ni] = 0.f; cq[ni] = 0.f; }
    }
#pragma unroll
    for (int pass = 0; pass < 2; ++pass) {
        if (wm == pass) {
#pragma unroll
            for (int ni = 0; ni < 4; ++ni) {
                int c = wn * 64 + ni * 16 + l15;
                float bvs = bias[colbase + c];
#pragma unroll
                for (int mi = 0; mi < 4; ++mi) {
#pragma unroll
                    for (int r = 0; r < 4; ++r) {
                        int rloc = mi * 16 + lg * 4 + r;  // 0..63 within half
                        float t = acc[mi][ni][r] + bvs;
                        t = (ACT == 0) ? fmaxf(t, 0.f) : selu_f(t);
                        if (STATS && (rowbase + pass * 64 + rloc < M)) { cs[ni] += t; cq[ni] += t * t; }
                        int byte = (rloc * 256 + c * 2) ^ ((rloc & 7) << 4);
                        *(unsigned short*)(smem + byte) = f2bf(t);
                    }
                }
            }
        }
        __syncthreads();
#pragma unroll
        for (int it = 0; it < 4; ++it) {
            int idx = it * 256 + tid;
            int row = idx >> 4;   // 0..63
            int ch = idx & 15;
            int gr = rowbase + pass * 64 + row;
            if (gr < M) {
                uint4 v = *(const uint4*)(smem + row * 256 + ((ch ^ (row & 7)) << 4));
                *(uint4*)(Out + (size_t)gr * NC + colbase + ch * 8) = v;
            }
        }
        __syncthreads();
    }
    if (STATS) {
        float* sS = (float*)(smem + 16384);  // [wm][kind][128]
#pragma unroll
        for (int ni = 0; ni < 4; ++ni) {
            float a = cs[ni];
            a += __shfl_xor(a, 16); a += __shfl_xor(a, 32);
            float b = cq[ni];
            b += __shfl_xor(b, 16); b += __shfl_xor(b, 32);
            if (lg == 0) {
                sS[wm * 256 + (wn * 64 + ni * 16 + l15)] = a;
                sS[wm * 256 + 128 + (wn * 64 + ni * 16 + l15)] = b;
            }
        }
        __syncthreads();
        int c = tid & 127, kind = tid >> 7;
        if (tid < 256) {
            float v = sS[kind * 128 + c] + sS[256 + kind * 128 + c];
            scratch[(size_t)(rb * 4 + cb) * 256 + kind * 128 + c] = v;
        }
    }
}

// ---------- BN1 partial reduce ----------
__global__ __launch_bounds__(256) void k_bnred(const float* __restrict__ scratch,
                                               float* __restrict__ bn) {
    int t = threadIdx.x;
    float loc[4] = {0.f, 0.f, 0.f, 0.f};
    for (int rb = blockIdx.x; rb < RB_COUNT; rb += gridDim.x) {
#pragma unroll
        for (int cbk = 0; cbk < 4; ++cbk)
            loc[cbk] += scratch[(size_t)(rb * 4 + cbk) * 256 + t];
    }
    int kind = t >> 7, cl = t & 127;
#pragma unroll
    for (int cbk = 0; cbk < 4; ++cbk)
        atomicAdd(&bn[kind * HID + cbk * 128 + cl], loc[cbk]);
}

// ---------- register-direct MFMA GEMM (final small GEMM, f32 out, fused BN2 stats) ----------
template <int K, int NC, int ACT, int WAVES_M, int WAVES_N, int NFRAG, int STATS, typename TOUT>
__global__ __launch_bounds__(WAVES_M * WAVES_N * 64) void k_mgemm(
    const unsigned short* __restrict__ A, const unsigned short* __restrict__ Wp,
    const float* __restrict__ bias, TOUT* __restrict__ Out, float* __restrict__ bnacc, int M) {
    __shared__ float sS[WAVES_M * WAVES_N * 128];
    const int tid = threadIdx.x;
    const int lane = tid & 63;
    const int w = tid >> 6;
    const int wm = w / WAVES_N;
    const int wn = w % WAVES_N;
    const int l15 = lane & 15;
    const int lg = lane >> 4;
    const int rowbase = blockIdx.x * (32 * WAVES_M) + wm * 32;
    const int colbase = blockIdx.y * (WAVES_N * 16 * NFRAG) + wn * 16 * NFRAG;
    int r0 = rowbase + l15; if (r0 > M - 1) r0 = M - 1;
    int r1 = rowbase + 16 + l15; if (r1 > M - 1) r1 = M - 1;
    const unsigned short* pa0 = A + (size_t)r0 * K + lg * 8;
    const unsigned short* pa1 = A + (size_t)r1 * K + lg * 8;
    const unsigned short* pw = Wp + (size_t)(colbase >> 4) * (K / 32) * 512 + lane * 8;

    f32x4 acc[2][NFRAG];
#pragma unroll
    for (int i = 0; i < 2; ++i)
#pragma unroll
        for (int j = 0; j < NFRAG; ++j) acc[i][j] = (f32x4)0.f;

#pragma unroll 2
    for (int kt = 0; kt < K / 32; ++kt) {
        bf16x8 a0 = *(const bf16x8*)(pa0 + kt * 32);
        bf16x8 a1 = *(const bf16x8*)(pa1 + kt * 32);
#pragma unroll
        for (int ni = 0; ni < NFRAG; ++ni) {
            bf16x8 bv = *(const bf16x8*)(pw + (ni * (K / 32) + kt) * 512);
            acc[0][ni] = __builtin_amdgcn_mfma_f32_16x16x32_bf16(a0, bv, acc[0][ni], 0, 0, 0);
            acc[1][ni] = __builtin_amdgcn_mfma_f32_16x16x32_bf16(a1, bv, acc[1][ni], 0, 0, 0);
        }
    }

    float cs[NFRAG], cq[NFRAG];
    if (STATS) {
#pragma unroll
        for (int ni = 0; ni < NFRAG; ++ni) { cs[ni] = 0.f; cq[ni] = 0.f; }
    }
#pragma unroll
    for (int ni = 0; ni < NFRAG; ++ni) {
        int c = colbase + ni * 16 + l15;
        float bv = bias[c];
#pragma unroll
        for (int mi = 0; mi < 2; ++mi) {
#pragma unroll
            for (int r = 0; r < 4; ++r) {
                int row = rowbase + mi * 16 + lg * 4 + r;
                if (row < M) {
                    float t = acc[mi][ni][r] + bv;
                    t = (ACT == 0) ? fmaxf(t, 0.f) : selu_f(t);
                    if (STATS) { cs[ni] += t; cq[ni] += t * t; }
                    stb(&Out[(size_t)row * NC + c], t);
                }
            }
        }
    }
    if (STATS) {
#pragma unroll
        for (int ni = 0; ni < NFRAG; ++ni) {
            float a = cs[ni];
            a += __shfl_xor(a, 16); a += __shfl_xor(a, 32);
            float b = cq[ni];
            b += __shfl_xor(b, 16); b += __shfl_xor(b, 32);
            if (lg == 0) {
                sS[w * 128 + (ni * 16 + l15)] = a;
                sS[w * 128 + 64 + (ni * 16 + l15)] = b;
            }
        }
        __syncthreads();
        if (tid < 128) {
            float v = 0.f;
#pragma unroll
            for (int ww = 0; ww < WAVES_M * WAVES_N; ++ww) v += sS[ww * 128 + tid];
            atomicAdd(&bnacc[tid], v);
        }
    }
}

// ---------- BN prep / softmax ----------
__global__ void k_bnprep(float* __restrict__ bn, const float* __restrict__ gamma,
                         const float* __restrict__ beta, int C, float invn) {
    int c = threadIdx.x + blockIdx.x * blockDim.x;
    if (c >= C) return;
    float mu = bn[c] * invn;
    float var = bn[C + c] * invn - mu * mu;
    float sc = gamma[c] * rsqrtf(var + 1e-5f);
    bn[2 * C + c] = sc;
    bn[3 * C + c] = beta[c] - mu * sc;
}

__global__ __launch_bounds__(256) void k_softmax(float* __restrict__ O, const float* __restrict__ bn2) {
    int w = (blockIdx.x * 256 + threadIdx.x) >> 6;
    if (w >= N_NODES) return;
    int lane = threadIdx.x & 63;
    float z = O[(size_t)w * NCLS + lane] * bn2[2 * NCLS + lane] + bn2[3 * NCLS + lane];
    float m = z;
#pragma unroll
    for (int o = 32; o > 0; o >>= 1) m = fmaxf(m, __shfl_xor(m, o));
    float e = __expf(z - m);
    float s = e;
#pragma unroll
    for (int o = 32; o > 0; o >>= 1) s += __shfl_xor(s, o);
    O[(size_t)w * NCLS + lane] = e / s;
}

// ---------- launch ----------
extern "C" void kernel_launch(void* const* d_in, const int* in_sizes, int n_in,
                              void* d_out, int out_size, void* d_ws, size_t ws_size,
                              hipStream_t stream) {
    const float* x = (const float*)d_in[0];
    const int* edge = (const int*)d_in[1];
    const int* srcp = edge;
    const int* dstp = edge + N_EDGES;
    const float* W1a = (const float*)d_in[9];
    const float* b1a = (const float*)d_in[10];
    const float* W1b = (const float*)d_in[11];
    const float* b1b = (const float*)d_in[12];
    const float* gamma1 = (const float*)d_in[13];
    const float* beta1 = (const float*)d_in[14];
    const float* W2a = (const float*)d_in[15];
    const float* b2a = (const float*)d_in[16];
    const float* W2b = (const float*)d_in[17];
    const float* b2b = (const float*)d_in[18];
    const float* gamma2 = (const float*)d_in[19];
    const float* beta2 = (const float*)d_in[20];
    float* out = (float*)d_out;

    char* ws = (char*)d_ws;
    size_t o = 0;
    auto alloc = [&](size_t bytes) -> char* {
        char* p = ws + o;
        o = (o + bytes + 255) & ~(size_t)255;
        return p;
    };
    int* off = (int*)alloc((N_NODES + 1) * sizeof(int));
    int* deg = (int*)alloc(N_NODES * sizeof(int));
    int* pos = (int*)alloc(N_NODES * sizeof(int));
    int* adj = (int*)alloc(N_EDGES * sizeof(int));
    int* part = (int*)alloc(SCAN_NB * sizeof(int));
    int* base = (int*)alloc(SCAN_NB * sizeof(int));
    float* bn1 = (float*)alloc(4 * HID * sizeof(float));
    float* bn2 = (float*)alloc(4 * NCLS * sizeof(float));
    float* stat = (float*)alloc((size_t)RB_COUNT * 4 * 256 * sizeof(float));
    unsigned short* Wp1 = (unsigned short*)alloc((size_t)IN_DIM * HID * sizeof(unsigned short));
    unsigned short* Wp2 = (unsigned short*)alloc((size_t)HID * HID * sizeof(unsigned short));
    unsigned short* Wp3 = (unsigned short*)alloc((size_t)HID * HID * sizeof(unsigned short));
    unsigned short* Wp4 = (unsigned short*)alloc((size_t)HID * NCLS * sizeof(unsigned short));
    unsigned short* xb = (unsigned short*)alloc((size_t)N_NODES * IN_DIM * sizeof(unsigned short));
    unsigned short* A1 = (unsigned short*)alloc((size_t)N_NODES * IN_DIM * sizeof(unsigned short));
    unsigned short* B = (unsigned short*)alloc((size_t)N_NODES * HID * sizeof(unsigned short));
    unsigned short* C = (unsigned short*)alloc((size_t)N_NODES * HID * sizeof(unsigned short));

    hipMemsetAsync(deg, 0, N_NODES * sizeof(int), stream);
    hipMemsetAsync(bn1, 0, 2 * HID * sizeof(float), stream);
    hipMemsetAsync(bn2, 0, 2 * NCLS * sizeof(float), stream);

    int eb = (N_EDGES + 255) / 256;
    k_cast<<<(N_NODES * IN_DIM / 8 + 255) / 256, 256, 0, stream>>>(x, xb);
    k_deg<<<eb, 256, 0, stream>>>(dstp, deg);
    k_scan_part<<<SCAN_NB, 256, 0, stream>>>(deg, part);
    k_scan_mid<<<1, 128, 0, stream>>>(part, base, off);
    k_scan_fin<<<SCAN_NB, 256, 0, stream>>>(deg, base, off, pos);
    k_fill<<<eb, 256, 0, stream>>>(srcp, dstp, pos, adj);
    k_sortadj<<<(N_NODES + 255) / 256, 256, 0, stream>>>(off, adj);

    k_pack<<<(IN_DIM * HID) / 256, 256, 0, stream>>>(W1a, Wp1, IN_DIM, HID);
    k_pack<<<(HID * HID) / 256, 256, 0, stream>>>(W1b, Wp2, HID, HID);
    k_pack<<<(HID * HID) / 256, 256, 0, stream>>>(W2a, Wp3, HID, HID);
    k_pack<<<(HID * NCLS) / 256, 256, 0, stream>>>(W2b, Wp4, HID, NCLS);

    int nwb = (N_NODES * 64 + 255) / 256;  // one wave per node

    // layer 1
    k_agg1<<<nwb, 256, 0, stream>>>(xb, off, adj, A1);
    k_hgemm<IN_DIM, 0, 0><<<TG_GRID, 256, 0, stream>>>(A1, Wp1, b1a, B, nullptr, N_NODES);
    k_hgemm<HID, 1, 1><<<TG_GRID, 256, 0, stream>>>(B, Wp2, b1b, C, stat, N_NODES);
    k_bnred<<<32, 256, 0, stream>>>(stat, bn1);
    k_bnprep<<<2, 256, 0, stream>>>(bn1, gamma1, beta1, HID, 1.0f / N_NODES);

    // layer 2
    k_aggbn2<<<dim3(nwb, 2), 256, 0, stream>>>(C, off, adj, bn1, B);
    k_hgemm<HID, 0, 0><<<TG_GRID, 256, 0, stream>>>(B, Wp3, b2a, C, nullptr, N_NODES);
    k_mgemm<HID, NCLS, 1, 8, 1, 4, 1, float><<<dim3((N_NODES + 255) / 256, 1), 512, 0, stream>>>(C, Wp4, b2b, out, bn2, N_NODES);

    k_bnprep<<<1, 64, 0, stream>>>(bn2, gamma2, beta2, NCLS, 1.0f / N_NODES);
    k_softmax<<<nwb, 256, 0, stream>>>(out, bn2);
}

// Round 10
// 851.388 us; speedup vs baseline: 1.3084x; 1.1151x over previous
//
#include <hip/hip_runtime.h>
#include <hip/hip_bf16.h>

#define N_NODES 100000
#define N_EDGES 1600000
#define IN_DIM 128
#define HID 512
#define NCLS 64

typedef __attribute__((ext_vector_type(8))) short bf16x8;
typedef __attribute__((ext_vector_type(4))) float f32x4;

#define RB_COUNT 782   // ceil(N/128)
#define RB_PAD 784     // padded to multiple of 8
#define TG_GRID (RB_PAD * 4)

// ---------- helpers ----------
__device__ inline float bf2f(unsigned short b) {
    unsigned int u = ((unsigned int)b) << 16;
    return __builtin_bit_cast(float, u);
}
__device__ inline unsigned short f2bf(float f) {
    unsigned int u = __builtin_bit_cast(unsigned int, f);
    unsigned int lsb = (u >> 16) & 1u;
    u += 0x7fffu + lsb;
    return (unsigned short)(u >> 16);
}
__device__ inline float selu_f(float x) {
    const float scale = 1.0507009873554805f;
    const float alpha = 1.6732632423543772f;
    return x > 0.f ? scale * x : scale * alpha * (__expf(x) - 1.f);
}
__device__ inline void stb(float* p, float v) { *p = v; }
__device__ inline void stb(unsigned short* p, float v) { *p = f2bf(v); }

// global -> LDS async 16B copy. dst wave-uniform; HW writes lane i at dst + i*16.
__device__ inline void gl_lds16(const void* g, void* l) {
    __builtin_amdgcn_global_load_lds((const __attribute__((address_space(1))) void*)g,
                                     (__attribute__((address_space(3))) void*)l, 16, 0, 0);
}

// ---------- x -> bf16 ----------
__global__ __launch_bounds__(256) void k_cast(const float* __restrict__ x,
                                              unsigned short* __restrict__ xb) {
    size_t g = (size_t)blockIdx.x * 256 + threadIdx.x;
    size_t total = (size_t)N_NODES * IN_DIM / 8;
    if (g >= total) return;
    const float4* p = (const float4*)(x + g * 8);
    float4 v0 = p[0], v1 = p[1];
    uint4 o;
    o.x = (unsigned)f2bf(v0.x) | ((unsigned)f2bf(v0.y) << 16);
    o.y = (unsigned)f2bf(v0.z) | ((unsigned)f2bf(v0.w) << 16);
    o.z = (unsigned)f2bf(v1.x) | ((unsigned)f2bf(v1.y) << 16);
    o.w = (unsigned)f2bf(v1.z) | ((unsigned)f2bf(v1.w) << 16);
    ((uint4*)xb)[g] = o;
}

// ---------- CSR build ----------
__global__ __launch_bounds__(256) void k_deg(const int* __restrict__ dst, int* __restrict__ deg) {
    int e = blockIdx.x * 256 + threadIdx.x;
    if (e < N_EDGES) atomicAdd(&deg[dst[e]], 1);
}

#define SCAN_NB 98  // ceil(100000/1024)

__global__ __launch_bounds__(256) void k_scan_part(const int* __restrict__ deg, int* __restrict__ part) {
    __shared__ int sd[256];
    int b = blockIdx.x, t = threadIdx.x;
    int i0 = b * 1024 + t * 4;
    int s = 0;
#pragma unroll
    for (int k = 0; k < 4; ++k) if (i0 + k < N_NODES) s += deg[i0 + k];
    sd[t] = s;
    __syncthreads();
    for (int o = 128; o > 0; o >>= 1) {
        if (t < o) sd[t] += sd[t + o];
        __syncthreads();
    }
    if (t == 0) part[b] = sd[0];
}

__global__ __launch_bounds__(128) void k_scan_mid(const int* __restrict__ part, int* __restrict__ base,
                                                  int* __restrict__ off) {
    __shared__ int sp[128];
    int t = threadIdx.x;
    int v = (t < SCAN_NB) ? part[t] : 0;
    sp[t] = v;
    __syncthreads();
    for (int o = 1; o < 128; o <<= 1) {
        int tv = (t >= o) ? sp[t - o] : 0;
        __syncthreads();
        sp[t] += tv;
        __syncthreads();
    }
    if (t < SCAN_NB) base[t] = sp[t] - v;
    if (t == SCAN_NB - 1) off[N_NODES] = sp[t];
}

__global__ __launch_bounds__(256) void k_scan_fin(const int* __restrict__ deg, const int* __restrict__ base,
                                                  int* __restrict__ off, int* __restrict__ pos) {
    __shared__ int sd[256];
    int b = blockIdx.x, t = threadIdx.x;
    int i0 = b * 1024 + t * 4;
    int v[4]; int s = 0;
#pragma unroll
    for (int k = 0; k < 4; ++k) { v[k] = (i0 + k < N_NODES) ? deg[i0 + k] : 0; s += v[k]; }
    sd[t] = s;
    __syncthreads();
    for (int o = 1; o < 256; o <<= 1) {
        int tv = (t >= o) ? sd[t - o] : 0;
        __syncthreads();
        sd[t] += tv;
        __syncthreads();
    }
    int excl = base[b] + sd[t] - s;
#pragma unroll
    for (int k = 0; k < 4; ++k) {
        if (i0 + k < N_NODES) { off[i0 + k] = excl; pos[i0 + k] = excl; excl += v[k]; }
    }
}

__global__ __launch_bounds__(256) void k_fill(const int* __restrict__ src, const int* __restrict__ dst,
                                              int* __restrict__ pos, int* __restrict__ adj) {
    int e = blockIdx.x * 256 + threadIdx.x;
    if (e < N_EDGES) {
        int p = atomicAdd(&pos[dst[e]], 1);
        adj[p] = src[e];
    }
}

// ---------- sort each adjacency list by src id (banded temporal locality) ----------
__global__ __launch_bounds__(256) void k_sortadj(const int* __restrict__ off, int* __restrict__ adj) {
    __shared__ int sb[64 * 256];
    int n = blockIdx.x * 256 + threadIdx.x;
    if (n >= N_NODES) return;
    int t = threadIdx.x;
    int e0 = off[n], e1 = off[n + 1];
    int d = e1 - e0;
    if (d <= 1 || d > 64) return;
    for (int i = 0; i < d; ++i) sb[i * 256 + t] = adj[e0 + i];
    for (int i = 1; i < d; ++i) {
        int key = sb[i * 256 + t];
        int j = i - 1;
        while (j >= 0 && sb[j * 256 + t] > key) {
            sb[(j + 1) * 256 + t] = sb[j * 256 + t];
            --j;
        }
        sb[(j + 1) * 256 + t] = key;
    }
    for (int i = 0; i < d; ++i) adj[e0 + i] = sb[i * 256 + t];
}

// ---------- weight packs ----------
__global__ __launch_bounds__(256) void k_pack(const float* __restrict__ W,
                                              unsigned short* __restrict__ Wp, int K, int NC) {
    int idx = blockIdx.x * 256 + threadIdx.x;
    if (idx >= K * NC) return;
    int j = idx & 7;
    int l = (idx >> 3) & 63;
    int t = idx >> 9;
    int KT = K >> 5;
    int kt = t % KT;
    int nt = t / KT;
    int k = kt * 32 + (l >> 4) * 8 + j;
    int n = nt * 16 + (l & 15);
    Wp[idx] = f2bf(W[(size_t)k * NC + n]);
}

__global__ __launch_bounds__(256) void k_packT(const float* __restrict__ W,
                                               unsigned short* __restrict__ WT, int K, int NC) {
    int idx = blockIdx.x * 256 + threadIdx.x;
    if (idx >= K * NC) return;
    int k = idx & (K - 1);
    int n = idx / K;
    WT[idx] = f2bf(W[(size_t)k * NC + n]);
}

// ---------- aggregation layer 1 ----------
__global__ __launch_bounds__(256) void k_agg1(const unsigned short* __restrict__ xb,
                                              const int* __restrict__ off, const int* __restrict__ adj,
                                              unsigned short* __restrict__ A1) {
    int w = (blockIdx.x * 256 + threadIdx.x) >> 6;
    if (w >= N_NODES) return;
    int lane = threadIdx.x & 63;
    unsigned v = ((const unsigned*)(xb + (size_t)w * IN_DIM))[lane];
    float s0 = bf2f((unsigned short)(v & 0xffff));
    float s1 = bf2f((unsigned short)(v >> 16));
    int e0 = off[w], e1 = off[w + 1];
    int e = e0;
    for (; e + 4 <= e1; e += 4) {
        int j0 = adj[e], j1 = adj[e + 1], j2 = adj[e + 2], j3 = adj[e + 3];
        unsigned u0 = ((const unsigned*)(xb + (size_t)j0 * IN_DIM))[lane];
        unsigned u1 = ((const unsigned*)(xb + (size_t)j1 * IN_DIM))[lane];
        unsigned u2 = ((const unsigned*)(xb + (size_t)j2 * IN_DIM))[lane];
        unsigned u3 = ((const unsigned*)(xb + (size_t)j3 * IN_DIM))[lane];
        s0 += bf2f((unsigned short)(u0 & 0xffff)) + bf2f((unsigned short)(u1 & 0xffff)) +
              bf2f((unsigned short)(u2 & 0xffff)) + bf2f((unsigned short)(u3 & 0xffff));
        s1 += bf2f((unsigned short)(u0 >> 16)) + bf2f((unsigned short)(u1 >> 16)) +
              bf2f((unsigned short)(u2 >> 16)) + bf2f((unsigned short)(u3 >> 16));
    }
    for (; e < e1; ++e) {
        unsigned u = ((const unsigned*)(xb + (size_t)adj[e] * IN_DIM))[lane];
        s0 += bf2f((unsigned short)(u & 0xffff));
        s1 += bf2f((unsigned short)(u >> 16));
    }
    ((unsigned*)(A1 + (size_t)w * IN_DIM))[lane] = (unsigned)f2bf(s0) | ((unsigned)f2bf(s1) << 16);
}

// ---------- aggregation layer 2, feature-sliced, BN1 fused ----------
__global__ __launch_bounds__(256) void k_aggbn2(const unsigned short* __restrict__ h,
                                                const int* __restrict__ off, const int* __restrict__ adj,
                                                const float* __restrict__ bn,
                                                unsigned short* __restrict__ outb) {
    int w = (blockIdx.x * 256 + threadIdx.x) >> 6;
    if (w >= N_NODES) return;
    int lane = threadIdx.x & 63;
    int fb = blockIdx.y * 256 + lane * 4;
    const unsigned short* hp = h + fb;
    float scl[4], shf[4];
#pragma unroll
    for (int k = 0; k < 4; ++k) {
        scl[k] = bn[2 * HID + fb + k];
        shf[k] = bn[3 * HID + fb + k];
    }
    uint2 v = *(const uint2*)(hp + (size_t)w * HID);
    float s0 = bf2f((unsigned short)(v.x & 0xffff));
    float s1 = bf2f((unsigned short)(v.x >> 16));
    float s2 = bf2f((unsigned short)(v.y & 0xffff));
    float s3 = bf2f((unsigned short)(v.y >> 16));
    int e0 = off[w], e1 = off[w + 1];
    int e = e0;
    for (; e + 4 <= e1; e += 4) {
        int j0 = adj[e], j1 = adj[e + 1], j2 = adj[e + 2], j3 = adj[e + 3];
        uint2 u0 = *(const uint2*)(hp + (size_t)j0 * HID);
        uint2 u1 = *(const uint2*)(hp + (size_t)j1 * HID);
        uint2 u2 = *(const uint2*)(hp + (size_t)j2 * HID);
        uint2 u3 = *(const uint2*)(hp + (size_t)j3 * HID);
        s0 += bf2f((unsigned short)(u0.x & 0xffff)) + bf2f((unsigned short)(u1.x & 0xffff)) +
              bf2f((unsigned short)(u2.x & 0xffff)) + bf2f((unsigned short)(u3.x & 0xffff));
        s1 += bf2f((unsigned short)(u0.x >> 16)) + bf2f((unsigned short)(u1.x >> 16)) +
              bf2f((unsigned short)(u2.x >> 16)) + bf2f((unsigned short)(u3.x >> 16));
        s2 += bf2f((unsigned short)(u0.y & 0xffff)) + bf2f((unsigned short)(u1.y & 0xffff)) +
              bf2f((unsigned short)(u2.y & 0xffff)) + bf2f((unsigned short)(u3.y & 0xffff));
        s3 += bf2f((unsigned short)(u0.y >> 16)) + bf2f((unsigned short)(u1.y >> 16)) +
              bf2f((unsigned short)(u2.y >> 16)) + bf2f((unsigned short)(u3.y >> 16));
    }
    for (; e < e1; ++e) {
        uint2 u = *(const uint2*)(hp + (size_t)adj[e] * HID);
        s0 += bf2f((unsigned short)(u.x & 0xffff));
        s1 += bf2f((unsigned short)(u.x >> 16));
        s2 += bf2f((unsigned short)(u.y & 0xffff));
        s3 += bf2f((unsigned short)(u.y >> 16));
    }
    float dp1 = (float)(e1 - e0 + 1);
    float r0 = s0 * scl[0] + dp1 * shf[0];
    float r1 = s1 * scl[1] + dp1 * shf[1];
    float r2 = s2 * scl[2] + dp1 * shf[2];
    float r3 = s3 * scl[3] + dp1 * shf[3];
    unsigned long long o =
        (unsigned long long)((unsigned)f2bf(r0) | ((unsigned)f2bf(r1) << 16)) |
        ((unsigned long long)((unsigned)f2bf(r2) | ((unsigned)f2bf(r3) << 16)) << 32);
    __builtin_nontemporal_store(o, (unsigned long long*)(outb + (size_t)w * HID + fb));
}

// ---------- LDS-staged MFMA GEMM, double-buffered 2-phase pipeline ----------
// Out[M,512] = act(A[M,K] @ W + bias). Tile 128x128, BK=64, 4 waves, XCD-grouped mapping.
// Pipeline (T3 minimum-2-phase): prologue stage(buf0); loop { stage(buf^1, next); compute(buf);
// __syncthreads(); flip } — one barrier per K-step, DMA overlaps MFMA.
template <int K, int ACT, int STATS>
__global__ __launch_bounds__(256) void k_tgemm(const unsigned short* __restrict__ A,
                                               const unsigned short* __restrict__ WT,
                                               const float* __restrict__ bias,
                                               unsigned short* __restrict__ Out,
                                               float* __restrict__ scratch, int M) {
    constexpr int NC = 512;
    constexpr int NSTEP = K / 64;
    __shared__ __align__(16) char smem[65536 + 2048];  // 2 x (A 16K + B 16K) + stats
    const int bid = blockIdx.x;
    const int r8 = bid & 7;
    const int q = bid >> 3;
    const int cb = q & 3;
    const int rb = (q >> 2) * 8 + r8;
    const int rowbase = rb * 128;
    const int colbase = cb * 128;
    if (rowbase >= M) return;

    const int tid = threadIdx.x;
    const int lane = tid & 63;
    const int w = tid >> 6;
    const int wm = w >> 1, wn = w & 1;
    const int l15 = lane & 15, lg = lane >> 4;

    // per-thread staging addresses (slot-invariant parts)
    const int slot_r = tid >> 3;          // row/col index contribution for i=0
    f32x4 acc[4][4];
#pragma unroll
    for (int i = 0; i < 4; ++i)
#pragma unroll
        for (int j = 0; j < 4; ++j) acc[i][j] = (f32x4)0.f;

    auto stage = [&](int buf, int k0) {
        char* sb = smem + buf * 32768;
#pragma unroll
        for (int i = 0; i < 4; ++i) {
            int slot = i * 256 + tid;
            int r = slot >> 3;
            int u = (slot & 7) ^ (r & 7);
            int gr = rowbase + r; if (gr >= M) gr = M - 1;
            gl_lds16(A + (size_t)gr * K + k0 + u * 8, sb + (i * 256 + w * 64) * 16);
        }
#pragma unroll
        for (int i = 0; i < 4; ++i) {
            int slot = i * 256 + tid;
            int c = slot >> 3;
            int u = (slot & 7) ^ (c & 7);
            gl_lds16(WT + (size_t)(colbase + c) * K + k0 + u * 8,
                     sb + 16384 + (i * 256 + w * 64) * 16);
        }
    };

    stage(0, 0);
    __syncthreads();
    int cur = 0;
    for (int ks = 0; ks < NSTEP; ++ks) {
        if (ks + 1 < NSTEP) stage(cur ^ 1, (ks + 1) * 64);
        const char* sb = smem + cur * 32768;
#pragma unroll
        for (int kin = 0; kin < 2; ++kin) {
            bf16x8 af[4], bfr[4];
#pragma unroll
            for (int mi = 0; mi < 4; ++mi) {
                int r = wm * 64 + mi * 16 + l15;
                int u = (kin * 4 + lg) ^ (r & 7);
                af[mi] = *(const bf16x8*)(sb + r * 128 + u * 16);
            }
#pragma unroll
            for (int ni = 0; ni < 4; ++ni) {
                int c = wn * 64 + ni * 16 + l15;
                int u = (kin * 4 + lg) ^ (c & 7);
                bfr[ni] = *(const bf16x8*)(sb + 16384 + c * 128 + u * 16);
            }
#pragma unroll
            for (int mi = 0; mi < 4; ++mi)
#pragma unroll
                for (int ni = 0; ni < 4; ++ni)
                    acc[mi][ni] = __builtin_amdgcn_mfma_f32_16x16x32_bf16(af[mi], bfr[ni], acc[mi][ni], 0, 0, 0);
        }
        __syncthreads();   // drains this iter's stage (next tile ready) + protects buffer reuse
        cur ^= 1;
    }
    (void)slot_r;

    // epilogue: bias+act -> LDS bf16 [128][128] tile in buffers 0..32KB -> coalesced stores
    float cs[4], cq[4];
    if (STATS) {
#pragma unroll
        for (int ni = 0; ni < 4; ++ni) { cs[ni] = 0.f; cq[ni] = 0.f; }
    }
#pragma unroll
    for (int ni = 0; ni < 4; ++ni) {
        int c = wn * 64 + ni * 16 + l15;
        float bv = bias[colbase + c];
#pragma unroll
        for (int mi = 0; mi < 4; ++mi) {
#pragma unroll
            for (int r = 0; r < 4; ++r) {
                int row = wm * 64 + mi * 16 + lg * 4 + r;
                float t = acc[mi][ni][r] + bv;
                t = (ACT == 0) ? fmaxf(t, 0.f) : selu_f(t);
                if (STATS && (rowbase + row < M)) { cs[ni] += t; cq[ni] += t * t; }
                int byte = (row * 256 + c * 2) ^ ((row & 7) << 4);
                *(unsigned short*)(smem + byte) = f2bf(t);
            }
        }
    }
    if (STATS) {
        float* sS = (float*)(smem + 65536);  // [wm][kind][128]
#pragma unroll
        for (int ni = 0; ni < 4; ++ni) {
            float a = cs[ni];
            a += __shfl_xor(a, 16); a += __shfl_xor(a, 32);
            float b = cq[ni];
            b += __shfl_xor(b, 16); b += __shfl_xor(b, 32);
            if (lg == 0) {
                sS[wm * 256 + (wn * 64 + ni * 16 + l15)] = a;
                sS[wm * 256 + 128 + (wn * 64 + ni * 16 + l15)] = b;
            }
        }
    }
    __syncthreads();
#pragma unroll
    for (int it = 0; it < 8; ++it) {
        int idx = it * 256 + tid;
        int row = idx >> 4;
        int ch = idx & 15;
        int gr = rowbase + row;
        if (gr < M) {
            uint4 v = *(const uint4*)(smem + row * 256 + ((ch ^ (row & 7)) << 4));
            *(uint4*)(Out + (size_t)gr * NC + colbase + ch * 8) = v;
        }
    }
    if (STATS) {
        const float* sS = (const float*)(smem + 65536);
        int c = tid & 127, kind = tid >> 7;
        float v = sS[kind * 128 + c] + sS[256 + kind * 128 + c];
        scratch[(size_t)(rb * 4 + cb) * 256 + kind * 128 + c] = v;
    }
}

// ---------- BN1 partial reduce ----------
__global__ __launch_bounds__(256) void k_bnred(const float* __restrict__ scratch,
                                               float* __restrict__ bn) {
    int t = threadIdx.x;
    float loc[4] = {0.f, 0.f, 0.f, 0.f};
    for (int rb = blockIdx.x; rb < RB_COUNT; rb += gridDim.x) {
#pragma unroll
        for (int cbk = 0; cbk < 4; ++cbk)
            loc[cbk] += scratch[(size_t)(rb * 4 + cbk) * 256 + t];
    }
    int kind = t >> 7, cl = t & 127;
#pragma unroll
    for (int cbk = 0; cbk < 4; ++cbk)
        atomicAdd(&bn[kind * HID + cbk * 128 + cl], loc[cbk]);
}

// ---------- register-direct MFMA GEMM (final small GEMM, f32 out, fused BN2 stats) ----------
template <int K, int NC, int ACT, int WAVES_M, int WAVES_N, int NFRAG, int STATS, typename TOUT>
__global__ __launch_bounds__(WAVES_M * WAVES_N * 64) void k_mgemm(
    const unsigned short* __restrict__ A, const unsigned short* __restrict__ Wp,
    const float* __restrict__ bias, TOUT* __restrict__ Out, float* __restrict__ bnacc, int M) {
    __shared__ float sS[WAVES_M * WAVES_N * 128];
    const int tid = threadIdx.x;
    const int lane = tid & 63;
    const int w = tid >> 6;
    const int wm = w / WAVES_N;
    const int wn = w % WAVES_N;
    const int l15 = lane & 15;
    const int lg = lane >> 4;
    const int rowbase = blockIdx.x * (32 * WAVES_M) + wm * 32;
    const int colbase = blockIdx.y * (WAVES_N * 16 * NFRAG) + wn * 16 * NFRAG;
    int r0 = rowbase + l15; if (r0 > M - 1) r0 = M - 1;
    int r1 = rowbase + 16 + l15; if (r1 > M - 1) r1 = M - 1;
    const unsigned short* pa0 = A + (size_t)r0 * K + lg * 8;
    const unsigned short* pa1 = A + (size_t)r1 * K + lg * 8;
    const unsigned short* pw = Wp + (size_t)(colbase >> 4) * (K / 32) * 512 + lane * 8;

    f32x4 acc[2][NFRAG];
#pragma unroll
    for (int i = 0; i < 2; ++i)
#pragma unroll
        for (int j = 0; j < NFRAG; ++j) acc[i][j] = (f32x4)0.f;

#pragma unroll 2
    for (int kt = 0; kt < K / 32; ++kt) {
        bf16x8 a0 = *(const bf16x8*)(pa0 + kt * 32);
        bf16x8 a1 = *(const bf16x8*)(pa1 + kt * 32);
#pragma unroll
        for (int ni = 0; ni < NFRAG; ++ni) {
            bf16x8 bv = *(const bf16x8*)(pw + (ni * (K / 32) + kt) * 512);
            acc[0][ni] = __builtin_amdgcn_mfma_f32_16x16x32_bf16(a0, bv, acc[0][ni], 0, 0, 0);
            acc[1][ni] = __builtin_amdgcn_mfma_f32_16x16x32_bf16(a1, bv, acc[1][ni], 0, 0, 0);
        }
    }

    float cs[NFRAG], cq[NFRAG];
    if (STATS) {
#pragma unroll
        for (int ni = 0; ni < NFRAG; ++ni) { cs[ni] = 0.f; cq[ni] = 0.f; }
    }
#pragma unroll
    for (int ni = 0; ni < NFRAG; ++ni) {
        int c = colbase + ni * 16 + l15;
        float bv = bias[c];
#pragma unroll
        for (int mi = 0; mi < 2; ++mi) {
#pragma unroll
            for (int r = 0; r < 4; ++r) {
                int row = rowbase + mi * 16 + lg * 4 + r;
                if (row < M) {
                    float t = acc[mi][ni][r] + bv;
                    t = (ACT == 0) ? fmaxf(t, 0.f) : selu_f(t);
                    if (STATS) { cs[ni] += t; cq[ni] += t * t; }
                    stb(&Out[(size_t)row * NC + c], t);
                }
            }
        }
    }
    if (STATS) {
#pragma unroll
        for (int ni = 0; ni < NFRAG; ++ni) {
            float a = cs[ni];
            a += __shfl_xor(a, 16); a += __shfl_xor(a, 32);
            float b = cq[ni];
            b += __shfl_xor(b, 16); b += __shfl_xor(b, 32);
            if (lg == 0) {
                sS[w * 128 + (ni * 16 + l15)] = a;
                sS[w * 128 + 64 + (ni * 16 + l15)] = b;
            }
        }
        __syncthreads();
        if (tid < 128) {
            float v = 0.f;
#pragma unroll
            for (int ww = 0; ww < WAVES_M * WAVES_N; ++ww) v += sS[ww * 128 + tid];
            atomicAdd(&bnacc[tid], v);
        }
    }
}

// ---------- BN prep / softmax ----------
__global__ void k_bnprep(float* __restrict__ bn, const float* __restrict__ gamma,
                         const float* __restrict__ beta, int C, float invn) {
    int c = threadIdx.x + blockIdx.x * blockDim.x;
    if (c >= C) return;
    float mu = bn[c] * invn;
    float var = bn[C + c] * invn - mu * mu;
    float sc = gamma[c] * rsqrtf(var + 1e-5f);
    bn[2 * C + c] = sc;
    bn[3 * C + c] = beta[c] - mu * sc;
}

__global__ __launch_bounds__(256) void k_softmax(float* __restrict__ O, const float* __restrict__ bn2) {
    int w = (blockIdx.x * 256 + threadIdx.x) >> 6;
    if (w >= N_NODES) return;
    int lane = threadIdx.x & 63;
    float z = O[(size_t)w * NCLS + lane] * bn2[2 * NCLS + lane] + bn2[3 * NCLS + lane];
    float m = z;
#pragma unroll
    for (int o = 32; o > 0; o >>= 1) m = fmaxf(m, __shfl_xor(m, o));
    float e = __expf(z - m);
    float s = e;
#pragma unroll
    for (int o = 32; o > 0; o >>= 1) s += __shfl_xor(s, o);
    O[(size_t)w * NCLS + lane] = e / s;
}

// ---------- launch ----------
extern "C" void kernel_launch(void* const* d_in, const int* in_sizes, int n_in,
                              void* d_out, int out_size, void* d_ws, size_t ws_size,
                              hipStream_t stream) {
    const float* x = (const float*)d_in[0];
    const int* edge = (const int*)d_in[1];
    const int* srcp = edge;
    const int* dstp = edge + N_EDGES;
    const float* W1a = (const float*)d_in[9];
    const float* b1a = (const float*)d_in[10];
    const float* W1b = (const float*)d_in[11];
    const float* b1b = (const float*)d_in[12];
    const float* gamma1 = (const float*)d_in[13];
    const float* beta1 = (const float*)d_in[14];
    const float* W2a = (const float*)d_in[15];
    const float* b2a = (const float*)d_in[16];
    const float* W2b = (const float*)d_in[17];
    const float* b2b = (const float*)d_in[18];
    const float* gamma2 = (const float*)d_in[19];
    const float* beta2 = (const float*)d_in[20];
    float* out = (float*)d_out;

    char* ws = (char*)d_ws;
    size_t o = 0;
    auto alloc = [&](size_t bytes) -> char* {
        char* p = ws + o;
        o = (o + bytes + 255) & ~(size_t)255;
        return p;
    };
    int* off = (int*)alloc((N_NODES + 1) * sizeof(int));
    int* deg = (int*)alloc(N_NODES * sizeof(int));
    int* pos = (int*)alloc(N_NODES * sizeof(int));
    int* adj = (int*)alloc(N_EDGES * sizeof(int));
    int* part = (int*)alloc(SCAN_NB * sizeof(int));
    int* base = (int*)alloc(SCAN_NB * sizeof(int));
    float* bn1 = (float*)alloc(4 * HID * sizeof(float));
    float* bn2 = (float*)alloc(4 * NCLS * sizeof(float));
    float* stat = (float*)alloc((size_t)RB_COUNT * 4 * 256 * sizeof(float));
    unsigned short* WT1 = (unsigned short*)alloc((size_t)IN_DIM * HID * sizeof(unsigned short));
    unsigned short* WT2 = (unsigned short*)alloc((size_t)HID * HID * sizeof(unsigned short));
    unsigned short* WT3 = (unsigned short*)alloc((size_t)HID * HID * sizeof(unsigned short));
    unsigned short* Wp4 = (unsigned short*)alloc((size_t)HID * NCLS * sizeof(unsigned short));
    unsigned short* xb = (unsigned short*)alloc((size_t)N_NODES * IN_DIM * sizeof(unsigned short));
    unsigned short* A1 = (unsigned short*)alloc((size_t)N_NODES * IN_DIM * sizeof(unsigned short));
    unsigned short* B = (unsigned short*)alloc((size_t)N_NODES * HID * sizeof(unsigned short));
    unsigned short* C = (unsigned short*)alloc((size_t)N_NODES * HID * sizeof(unsigned short));

    hipMemsetAsync(deg, 0, N_NODES * sizeof(int), stream);
    hipMemsetAsync(bn1, 0, 2 * HID * sizeof(float), stream);
    hipMemsetAsync(bn2, 0, 2 * NCLS * sizeof(float), stream);

    int eb = (N_EDGES + 255) / 256;
    k_cast<<<(N_NODES * IN_DIM / 8 + 255) / 256, 256, 0, stream>>>(x, xb);
    k_deg<<<eb, 256, 0, stream>>>(dstp, deg);
    k_scan_part<<<SCAN_NB, 256, 0, stream>>>(deg, part);
    k_scan_mid<<<1, 128, 0, stream>>>(part, base, off);
    k_scan_fin<<<SCAN_NB, 256, 0, stream>>>(deg, base, off, pos);
    k_fill<<<eb, 256, 0, stream>>>(srcp, dstp, pos, adj);
    k_sortadj<<<(N_NODES + 255) / 256, 256, 0, stream>>>(off, adj);

    k_packT<<<(IN_DIM * HID) / 256, 256, 0, stream>>>(W1a, WT1, IN_DIM, HID);
    k_packT<<<(HID * HID) / 256, 256, 0, stream>>>(W1b, WT2, HID, HID);
    k_packT<<<(HID * HID) / 256, 256, 0, stream>>>(W2a, WT3, HID, HID);
    k_pack<<<(HID * NCLS) / 256, 256, 0, stream>>>(W2b, Wp4, HID, NCLS);

    int nwb = (N_NODES * 64 + 255) / 256;  // one wave per node

    // layer 1
    k_agg1<<<nwb, 256, 0, stream>>>(xb, off, adj, A1);
    k_tgemm<IN_DIM, 0, 0><<<TG_GRID, 256, 0, stream>>>(A1, WT1, b1a, B, nullptr, N_NODES);
    k_tgemm<HID, 1, 1><<<TG_GRID, 256, 0, stream>>>(B, WT2, b1b, C, stat, N_NODES);
    k_bnred<<<32, 256, 0, stream>>>(stat, bn1);
    k_bnprep<<<2, 256, 0, stream>>>(bn1, gamma1, beta1, HID, 1.0f / N_NODES);

    // layer 2
    k_aggbn2<<<dim3(nwb, 2), 256, 0, stream>>>(C, off, adj, bn1, B);
    k_tgemm<HID, 0, 0><<<TG_GRID, 256, 0, stream>>>(B, WT3, b2a, C, nullptr, N_NODES);
    k_mgemm<HID, NCLS, 1, 8, 1, 4, 1, float><<<dim3((N_NODES + 255) / 256, 1), 512, 0, stream>>>(C, Wp4, b2b, out, bn2, N_NODES);

    k_bnprep<<<1, 64, 0, stream>>>(bn2, gamma2, beta2, NCLS, 1.0f / N_NODES);
    k_softmax<<<nwb, 256, 0, stream>>>(out, bn2);
}

// Round 11
// 838.007 us; speedup vs baseline: 1.3293x; 1.0160x over previous
//
#include <hip/hip_runtime.h>
#include <hip/hip_bf16.h>

#define N_NODES 100000
#define N_EDGES 1600000
#define IN_DIM 128
#define HID 512
#define NCLS 64

typedef __attribute__((ext_vector_type(8))) short bf16x8;
typedef __attribute__((ext_vector_type(4))) float f32x4;

#define RB_COUNT 782   // ceil(N/128)
#define RB_PAD 784     // padded to multiple of 8
#define TG_GRID (RB_PAD * 4)

// ---------- helpers ----------
__device__ inline float bf2f(unsigned short b) {
    unsigned int u = ((unsigned int)b) << 16;
    return __builtin_bit_cast(float, u);
}
__device__ inline unsigned short f2bf(float f) {
    unsigned int u = __builtin_bit_cast(unsigned int, f);
    unsigned int lsb = (u >> 16) & 1u;
    u += 0x7fffu + lsb;
    return (unsigned short)(u >> 16);
}
__device__ inline float selu_f(float x) {
    const float scale = 1.0507009873554805f;
    const float alpha = 1.6732632423543772f;
    return x > 0.f ? scale * x : scale * alpha * (__expf(x) - 1.f);
}
__device__ inline void stb(float* p, float v) { *p = v; }
__device__ inline void stb(unsigned short* p, float v) { *p = f2bf(v); }

// global -> LDS async 16B copy. dst wave-uniform; HW writes lane i at dst + i*16.
__device__ inline void gl_lds16(const void* g, void* l) {
    __builtin_amdgcn_global_load_lds((const __attribute__((address_space(1))) void*)g,
                                     (__attribute__((address_space(3))) void*)l, 16, 0, 0);
}

// ---------- x -> bf16 ----------
__global__ __launch_bounds__(256) void k_cast(const float* __restrict__ x,
                                              unsigned short* __restrict__ xb) {
    size_t g = (size_t)blockIdx.x * 256 + threadIdx.x;
    size_t total = (size_t)N_NODES * IN_DIM / 8;
    if (g >= total) return;
    const float4* p = (const float4*)(x + g * 8);
    float4 v0 = p[0], v1 = p[1];
    uint4 o;
    o.x = (unsigned)f2bf(v0.x) | ((unsigned)f2bf(v0.y) << 16);
    o.y = (unsigned)f2bf(v0.z) | ((unsigned)f2bf(v0.w) << 16);
    o.z = (unsigned)f2bf(v1.x) | ((unsigned)f2bf(v1.y) << 16);
    o.w = (unsigned)f2bf(v1.z) | ((unsigned)f2bf(v1.w) << 16);
    ((uint4*)xb)[g] = o;
}

// ---------- CSR build ----------
__global__ __launch_bounds__(256) void k_deg(const int* __restrict__ dst, int* __restrict__ deg) {
    int e = blockIdx.x * 256 + threadIdx.x;
    if (e < N_EDGES) atomicAdd(&deg[dst[e]], 1);
}

#define SCAN_NB 98  // ceil(100000/1024)

__global__ __launch_bounds__(256) void k_scan_part(const int* __restrict__ deg, int* __restrict__ part) {
    __shared__ int sd[256];
    int b = blockIdx.x, t = threadIdx.x;
    int i0 = b * 1024 + t * 4;
    int s = 0;
#pragma unroll
    for (int k = 0; k < 4; ++k) if (i0 + k < N_NODES) s += deg[i0 + k];
    sd[t] = s;
    __syncthreads();
    for (int o = 128; o > 0; o >>= 1) {
        if (t < o) sd[t] += sd[t + o];
        __syncthreads();
    }
    if (t == 0) part[b] = sd[0];
}

__global__ __launch_bounds__(128) void k_scan_mid(const int* __restrict__ part, int* __restrict__ base,
                                                  int* __restrict__ off) {
    __shared__ int sp[128];
    int t = threadIdx.x;
    int v = (t < SCAN_NB) ? part[t] : 0;
    sp[t] = v;
    __syncthreads();
    for (int o = 1; o < 128; o <<= 1) {
        int tv = (t >= o) ? sp[t - o] : 0;
        __syncthreads();
        sp[t] += tv;
        __syncthreads();
    }
    if (t < SCAN_NB) base[t] = sp[t] - v;
    if (t == SCAN_NB - 1) off[N_NODES] = sp[t];
}

__global__ __launch_bounds__(256) void k_scan_fin(const int* __restrict__ deg, const int* __restrict__ base,
                                                  int* __restrict__ off, int* __restrict__ pos) {
    __shared__ int sd[256];
    int b = blockIdx.x, t = threadIdx.x;
    int i0 = b * 1024 + t * 4;
    int v[4]; int s = 0;
#pragma unroll
    for (int k = 0; k < 4; ++k) { v[k] = (i0 + k < N_NODES) ? deg[i0 + k] : 0; s += v[k]; }
    sd[t] = s;
    __syncthreads();
    for (int o = 1; o < 256; o <<= 1) {
        int tv = (t >= o) ? sd[t - o] : 0;
        __syncthreads();
        sd[t] += tv;
        __syncthreads();
    }
    int excl = base[b] + sd[t] - s;
#pragma unroll
    for (int k = 0; k < 4; ++k) {
        if (i0 + k < N_NODES) { off[i0 + k] = excl; pos[i0 + k] = excl; excl += v[k]; }
    }
}

__global__ __launch_bounds__(256) void k_fill(const int* __restrict__ src, const int* __restrict__ dst,
                                              int* __restrict__ pos, int* __restrict__ adj) {
    int e = blockIdx.x * 256 + threadIdx.x;
    if (e < N_EDGES) {
        int p = atomicAdd(&pos[dst[e]], 1);
        adj[p] = src[e];
    }
}

// ---------- sort each adjacency list by src id (banded temporal locality) ----------
__global__ __launch_bounds__(256) void k_sortadj(const int* __restrict__ off, int* __restrict__ adj) {
    __shared__ int sb[64 * 256];
    int n = blockIdx.x * 256 + threadIdx.x;
    if (n >= N_NODES) return;
    int t = threadIdx.x;
    int e0 = off[n], e1 = off[n + 1];
    int d = e1 - e0;
    if (d <= 1 || d > 64) return;
    for (int i = 0; i < d; ++i) sb[i * 256 + t] = adj[e0 + i];
    for (int i = 1; i < d; ++i) {
        int key = sb[i * 256 + t];
        int j = i - 1;
        while (j >= 0 && sb[j * 256 + t] > key) {
            sb[(j + 1) * 256 + t] = sb[j * 256 + t];
            --j;
        }
        sb[(j + 1) * 256 + t] = key;
    }
    for (int i = 0; i < d; ++i) adj[e0 + i] = sb[i * 256 + t];
}

// ---------- weight packs ----------
__global__ __launch_bounds__(256) void k_pack(const float* __restrict__ W,
                                              unsigned short* __restrict__ Wp, int K, int NC) {
    int idx = blockIdx.x * 256 + threadIdx.x;
    if (idx >= K * NC) return;
    int j = idx & 7;
    int l = (idx >> 3) & 63;
    int t = idx >> 9;
    int KT = K >> 5;
    int kt = t % KT;
    int nt = t / KT;
    int k = kt * 32 + (l >> 4) * 8 + j;
    int n = nt * 16 + (l & 15);
    Wp[idx] = f2bf(W[(size_t)k * NC + n]);
}

__global__ __launch_bounds__(256) void k_packT(const float* __restrict__ W,
                                               unsigned short* __restrict__ WT, int K, int NC) {
    int idx = blockIdx.x * 256 + threadIdx.x;
    if (idx >= K * NC) return;
    int k = idx & (K - 1);
    int n = idx / K;
    WT[idx] = f2bf(W[(size_t)k * NC + n]);
}

// ---------- aggregation layer 1: 8 rows in flight ----------
__global__ __launch_bounds__(256) void k_agg1(const unsigned short* __restrict__ xb,
                                              const int* __restrict__ off, const int* __restrict__ adj,
                                              unsigned short* __restrict__ A1) {
    int w = (blockIdx.x * 256 + threadIdx.x) >> 6;
    if (w >= N_NODES) return;
    int lane = threadIdx.x & 63;
    unsigned v = ((const unsigned*)(xb + (size_t)w * IN_DIM))[lane];
    float s0 = bf2f((unsigned short)(v & 0xffff));
    float s1 = bf2f((unsigned short)(v >> 16));
    int e0 = off[w], e1 = off[w + 1];
    int e = e0;
    for (; e + 8 <= e1; e += 8) {
        unsigned u[8];
#pragma unroll
        for (int q = 0; q < 8; ++q) {
            int j = adj[e + q];
            u[q] = ((const unsigned*)(xb + (size_t)j * IN_DIM))[lane];
        }
#pragma unroll
        for (int q = 0; q < 8; ++q) {
            s0 += bf2f((unsigned short)(u[q] & 0xffff));
            s1 += bf2f((unsigned short)(u[q] >> 16));
        }
    }
    for (; e + 4 <= e1; e += 4) {
        unsigned u[4];
#pragma unroll
        for (int q = 0; q < 4; ++q) {
            int j = adj[e + q];
            u[q] = ((const unsigned*)(xb + (size_t)j * IN_DIM))[lane];
        }
#pragma unroll
        for (int q = 0; q < 4; ++q) {
            s0 += bf2f((unsigned short)(u[q] & 0xffff));
            s1 += bf2f((unsigned short)(u[q] >> 16));
        }
    }
    for (; e < e1; ++e) {
        unsigned u = ((const unsigned*)(xb + (size_t)adj[e] * IN_DIM))[lane];
        s0 += bf2f((unsigned short)(u & 0xffff));
        s1 += bf2f((unsigned short)(u >> 16));
    }
    ((unsigned*)(A1 + (size_t)w * IN_DIM))[lane] = (unsigned)f2bf(s0) | ((unsigned)f2bf(s1) << 16);
}

// ---------- aggregation layer 2, feature-sliced, BN1 fused, 8 rows in flight ----------
__global__ __launch_bounds__(256) void k_aggbn2(const unsigned short* __restrict__ h,
                                                const int* __restrict__ off, const int* __restrict__ adj,
                                                const float* __restrict__ bn,
                                                unsigned short* __restrict__ outb) {
    int w = (blockIdx.x * 256 + threadIdx.x) >> 6;
    if (w >= N_NODES) return;
    int lane = threadIdx.x & 63;
    int fb = blockIdx.y * 256 + lane * 4;
    const unsigned short* hp = h + fb;
    float scl[4], shf[4];
#pragma unroll
    for (int k = 0; k < 4; ++k) {
        scl[k] = bn[2 * HID + fb + k];
        shf[k] = bn[3 * HID + fb + k];
    }
    uint2 v = *(const uint2*)(hp + (size_t)w * HID);
    float s0 = bf2f((unsigned short)(v.x & 0xffff));
    float s1 = bf2f((unsigned short)(v.x >> 16));
    float s2 = bf2f((unsigned short)(v.y & 0xffff));
    float s3 = bf2f((unsigned short)(v.y >> 16));
    int e0 = off[w], e1 = off[w + 1];
    int e = e0;
    for (; e + 8 <= e1; e += 8) {
        uint2 u[8];
#pragma unroll
        for (int q = 0; q < 8; ++q) {
            int j = adj[e + q];
            u[q] = *(const uint2*)(hp + (size_t)j * HID);
        }
#pragma unroll
        for (int q = 0; q < 8; ++q) {
            s0 += bf2f((unsigned short)(u[q].x & 0xffff));
            s1 += bf2f((unsigned short)(u[q].x >> 16));
            s2 += bf2f((unsigned short)(u[q].y & 0xffff));
            s3 += bf2f((unsigned short)(u[q].y >> 16));
        }
    }
    for (; e + 4 <= e1; e += 4) {
        uint2 u[4];
#pragma unroll
        for (int q = 0; q < 4; ++q) {
            int j = adj[e + q];
            u[q] = *(const uint2*)(hp + (size_t)j * HID);
        }
#pragma unroll
        for (int q = 0; q < 4; ++q) {
            s0 += bf2f((unsigned short)(u[q].x & 0xffff));
            s1 += bf2f((unsigned short)(u[q].x >> 16));
            s2 += bf2f((unsigned short)(u[q].y & 0xffff));
            s3 += bf2f((unsigned short)(u[q].y >> 16));
        }
    }
    for (; e < e1; ++e) {
        uint2 u = *(const uint2*)(hp + (size_t)adj[e] * HID);
        s0 += bf2f((unsigned short)(u.x & 0xffff));
        s1 += bf2f((unsigned short)(u.x >> 16));
        s2 += bf2f((unsigned short)(u.y & 0xffff));
        s3 += bf2f((unsigned short)(u.y >> 16));
    }
    float dp1 = (float)(e1 - e0 + 1);
    float r0 = s0 * scl[0] + dp1 * shf[0];
    float r1 = s1 * scl[1] + dp1 * shf[1];
    float r2 = s2 * scl[2] + dp1 * shf[2];
    float r3 = s3 * scl[3] + dp1 * shf[3];
    unsigned long long o =
        (unsigned long long)((unsigned)f2bf(r0) | ((unsigned)f2bf(r1) << 16)) |
        ((unsigned long long)((unsigned)f2bf(r2) | ((unsigned)f2bf(r3) << 16)) << 32);
    __builtin_nontemporal_store(o, (unsigned long long*)(outb + (size_t)w * HID + fb));
}

// ---------- LDS-staged MFMA GEMM, double-buffered 2-phase pipeline (proven round-10) ----------
template <int K, int ACT, int STATS>
__global__ __launch_bounds__(256) void k_tgemm(const unsigned short* __restrict__ A,
                                               const unsigned short* __restrict__ WT,
                                               const float* __restrict__ bias,
                                               unsigned short* __restrict__ Out,
                                               float* __restrict__ scratch, int M) {
    constexpr int NC = 512;
    constexpr int NSTEP = K / 64;
    __shared__ __align__(16) char smem[65536 + 2048];  // 2 x (A 16K + B 16K) + stats
    const int bid = blockIdx.x;
    const int r8 = bid & 7;
    const int q = bid >> 3;
    const int cb = q & 3;
    const int rb = (q >> 2) * 8 + r8;
    const int rowbase = rb * 128;
    const int colbase = cb * 128;
    if (rowbase >= M) return;

    const int tid = threadIdx.x;
    const int lane = tid & 63;
    const int w = tid >> 6;
    const int wm = w >> 1, wn = w & 1;
    const int l15 = lane & 15, lg = lane >> 4;

    f32x4 acc[4][4];
#pragma unroll
    for (int i = 0; i < 4; ++i)
#pragma unroll
        for (int j = 0; j < 4; ++j) acc[i][j] = (f32x4)0.f;

    auto stage = [&](int buf, int k0) {
        char* sb = smem + buf * 32768;
#pragma unroll
        for (int i = 0; i < 4; ++i) {
            int slot = i * 256 + tid;
            int r = slot >> 3;
            int u = (slot & 7) ^ (r & 7);
            int gr = rowbase + r; if (gr >= M) gr = M - 1;
            gl_lds16(A + (size_t)gr * K + k0 + u * 8, sb + (i * 256 + w * 64) * 16);
        }
#pragma unroll
        for (int i = 0; i < 4; ++i) {
            int slot = i * 256 + tid;
            int c = slot >> 3;
            int u = (slot & 7) ^ (c & 7);
            gl_lds16(WT + (size_t)(colbase + c) * K + k0 + u * 8,
                     sb + 16384 + (i * 256 + w * 64) * 16);
        }
    };

    stage(0, 0);
    __syncthreads();
    int cur = 0;
    for (int ks = 0; ks < NSTEP; ++ks) {
        if (ks + 1 < NSTEP) stage(cur ^ 1, (ks + 1) * 64);
        const char* sb = smem + cur * 32768;
#pragma unroll
        for (int kin = 0; kin < 2; ++kin) {
            bf16x8 af[4], bfr[4];
#pragma unroll
            for (int mi = 0; mi < 4; ++mi) {
                int r = wm * 64 + mi * 16 + l15;
                int u = (kin * 4 + lg) ^ (r & 7);
                af[mi] = *(const bf16x8*)(sb + r * 128 + u * 16);
            }
#pragma unroll
            for (int ni = 0; ni < 4; ++ni) {
                int c = wn * 64 + ni * 16 + l15;
                int u = (kin * 4 + lg) ^ (c & 7);
                bfr[ni] = *(const bf16x8*)(sb + 16384 + c * 128 + u * 16);
            }
#pragma unroll
            for (int mi = 0; mi < 4; ++mi)
#pragma unroll
                for (int ni = 0; ni < 4; ++ni)
                    acc[mi][ni] = __builtin_amdgcn_mfma_f32_16x16x32_bf16(af[mi], bfr[ni], acc[mi][ni], 0, 0, 0);
        }
        __syncthreads();
        cur ^= 1;
    }

    // epilogue: bias+act -> LDS bf16 [128][128] tile -> coalesced stores
    float cs[4], cq[4];
    if (STATS) {
#pragma unroll
        for (int ni = 0; ni < 4; ++ni) { cs[ni] = 0.f; cq[ni] = 0.f; }
    }
#pragma unroll
    for (int ni = 0; ni < 4; ++ni) {
        int c = wn * 64 + ni * 16 + l15;
        float bv = bias[colbase + c];
#pragma unroll
        for (int mi = 0; mi < 4; ++mi) {
#pragma unroll
            for (int r = 0; r < 4; ++r) {
                int row = wm * 64 + mi * 16 + lg * 4 + r;
                float t = acc[mi][ni][r] + bv;
                t = (ACT == 0) ? fmaxf(t, 0.f) : selu_f(t);
                if (STATS && (rowbase + row < M)) { cs[ni] += t; cq[ni] += t * t; }
                int byte = (row * 256 + c * 2) ^ ((row & 7) << 4);
                *(unsigned short*)(smem + byte) = f2bf(t);
            }
        }
    }
    if (STATS) {
        float* sS = (float*)(smem + 65536);  // [wm][kind][128]
#pragma unroll
        for (int ni = 0; ni < 4; ++ni) {
            float a = cs[ni];
            a += __shfl_xor(a, 16); a += __shfl_xor(a, 32);
            float b = cq[ni];
            b += __shfl_xor(b, 16); b += __shfl_xor(b, 32);
            if (lg == 0) {
                sS[wm * 256 + (wn * 64 + ni * 16 + l15)] = a;
                sS[wm * 256 + 128 + (wn * 64 + ni * 16 + l15)] = b;
            }
        }
    }
    __syncthreads();
#pragma unroll
    for (int it = 0; it < 8; ++it) {
        int idx = it * 256 + tid;
        int row = idx >> 4;
        int ch = idx & 15;
        int gr = rowbase + row;
        if (gr < M) {
            uint4 v = *(const uint4*)(smem + row * 256 + ((ch ^ (row & 7)) << 4));
            *(uint4*)(Out + (size_t)gr * NC + colbase + ch * 8) = v;
        }
    }
    if (STATS) {
        const float* sS = (const float*)(smem + 65536);
        int c = tid & 127, kind = tid >> 7;
        float v = sS[kind * 128 + c] + sS[256 + kind * 128 + c];
        scratch[(size_t)(rb * 4 + cb) * 256 + kind * 128 + c] = v;
    }
}

// ---------- BN1 partial reduce ----------
__global__ __launch_bounds__(256) void k_bnred(const float* __restrict__ scratch,
                                               float* __restrict__ bn) {
    int t = threadIdx.x;
    float loc[4] = {0.f, 0.f, 0.f, 0.f};
    for (int rb = blockIdx.x; rb < RB_COUNT; rb += gridDim.x) {
#pragma unroll
        for (int cbk = 0; cbk < 4; ++cbk)
            loc[cbk] += scratch[(size_t)(rb * 4 + cbk) * 256 + t];
    }
    int kind = t >> 7, cl = t & 127;
#pragma unroll
    for (int cbk = 0; cbk < 4; ++cbk)
        atomicAdd(&bn[kind * HID + cbk * 128 + cl], loc[cbk]);
}

// ---------- register-direct MFMA GEMM (final small GEMM, f32 out, fused BN2 stats) ----------
template <int K, int NC, int ACT, int WAVES_M, int WAVES_N, int NFRAG, int STATS, typename TOUT>
__global__ __launch_bounds__(WAVES_M * WAVES_N * 64) void k_mgemm(
    const unsigned short* __restrict__ A, const unsigned short* __restrict__ Wp,
    const float* __restrict__ bias, TOUT* __restrict__ Out, float* __restrict__ bnacc, int M) {
    __shared__ float sS[WAVES_M * WAVES_N * 128];
    const int tid = threadIdx.x;
    const int lane = tid & 63;
    const int w = tid >> 6;
    const int wm = w / WAVES_N;
    const int wn = w % WAVES_N;
    const int l15 = lane & 15;
    const int lg = lane >> 4;
    const int rowbase = blockIdx.x * (32 * WAVES_M) + wm * 32;
    const int colbase = blockIdx.y * (WAVES_N * 16 * NFRAG) + wn * 16 * NFRAG;
    int r0 = rowbase + l15; if (r0 > M - 1) r0 = M - 1;
    int r1 = rowbase + 16 + l15; if (r1 > M - 1) r1 = M - 1;
    const unsigned short* pa0 = A + (size_t)r0 * K + lg * 8;
    const unsigned short* pa1 = A + (size_t)r1 * K + lg * 8;
    const unsigned short* pw = Wp + (size_t)(colbase >> 4) * (K / 32) * 512 + lane * 8;

    f32x4 acc[2][NFRAG];
#pragma unroll
    for (int i = 0; i < 2; ++i)
#pragma unroll
        for (int j = 0; j < NFRAG; ++j) acc[i][j] = (f32x4)0.f;

#pragma unroll 2
    for (int kt = 0; kt < K / 32; ++kt) {
        bf16x8 a0 = *(const bf16x8*)(pa0 + kt * 32);
        bf16x8 a1 = *(const bf16x8*)(pa1 + kt * 32);
#pragma unroll
        for (int ni = 0; ni < NFRAG; ++ni) {
            bf16x8 bv = *(const bf16x8*)(pw + (ni * (K / 32) + kt) * 512);
            acc[0][ni] = __builtin_amdgcn_mfma_f32_16x16x32_bf16(a0, bv, acc[0][ni], 0, 0, 0);
            acc[1][ni] = __builtin_amdgcn_mfma_f32_16x16x32_bf16(a1, bv, acc[1][ni], 0, 0, 0);
        }
    }

    float cs[NFRAG], cq[NFRAG];
    if (STATS) {
#pragma unroll
        for (int ni = 0; ni < NFRAG; ++ni) { cs[ni] = 0.f; cq[ni] = 0.f; }
    }
#pragma unroll
    for (int ni = 0; ni < NFRAG; ++ni) {
        int c = colbase + ni * 16 + l15;
        float bv = bias[c];
#pragma unroll
        for (int mi = 0; mi < 2; ++mi) {
#pragma unroll
            for (int r = 0; r < 4; ++r) {
                int row = rowbase + mi * 16 + lg * 4 + r;
                if (row < M) {
                    float t = acc[mi][ni][r] + bv;
                    t = (ACT == 0) ? fmaxf(t, 0.f) : selu_f(t);
                    if (STATS) { cs[ni] += t; cq[ni] += t * t; }
                    stb(&Out[(size_t)row * NC + c], t);
                }
            }
        }
    }
    if (STATS) {
#pragma unroll
        for (int ni = 0; ni < NFRAG; ++ni) {
            float a = cs[ni];
            a += __shfl_xor(a, 16); a += __shfl_xor(a, 32);
            float b = cq[ni];
            b += __shfl_xor(b, 16); b += __shfl_xor(b, 32);
            if (lg == 0) {
                sS[w * 128 + (ni * 16 + l15)] = a;
                sS[w * 128 + 64 + (ni * 16 + l15)] = b;
            }
        }
        __syncthreads();
        if (tid < 128) {
            float v = 0.f;
#pragma unroll
            for (int ww = 0; ww < WAVES_M * WAVES_N; ++ww) v += sS[ww * 128 + tid];
            atomicAdd(&bnacc[tid], v);
        }
    }
}

// ---------- BN prep / softmax ----------
__global__ void k_bnprep(float* __restrict__ bn, const float* __restrict__ gamma,
                         const float* __restrict__ beta, int C, float invn) {
    int c = threadIdx.x + blockIdx.x * blockDim.x;
    if (c >= C) return;
    float mu = bn[c] * invn;
    float var = bn[C + c] * invn - mu * mu;
    float sc = gamma[c] * rsqrtf(var + 1e-5f);
    bn[2 * C + c] = sc;
    bn[3 * C + c] = beta[c] - mu * sc;
}

__global__ __launch_bounds__(256) void k_softmax(float* __restrict__ O, const float* __restrict__ bn2) {
    int w = (blockIdx.x * 256 + threadIdx.x) >> 6;
    if (w >= N_NODES) return;
    int lane = threadIdx.x & 63;
    float z = O[(size_t)w * NCLS + lane] * bn2[2 * NCLS + lane] + bn2[3 * NCLS + lane];
    float m = z;
#pragma unroll
    for (int o = 32; o > 0; o >>= 1) m = fmaxf(m, __shfl_xor(m, o));
    float e = __expf(z - m);
    float s = e;
#pragma unroll
    for (int o = 32; o > 0; o >>= 1) s += __shfl_xor(s, o);
    O[(size_t)w * NCLS + lane] = e / s;
}

// ---------- launch ----------
extern "C" void kernel_launch(void* const* d_in, const int* in_sizes, int n_in,
                              void* d_out, int out_size, void* d_ws, size_t ws_size,
                              hipStream_t stream) {
    const float* x = (const float*)d_in[0];
    const int* edge = (const int*)d_in[1];
    const int* srcp = edge;
    const int* dstp = edge + N_EDGES;
    const float* W1a = (const float*)d_in[9];
    const float* b1a = (const float*)d_in[10];
    const float* W1b = (const float*)d_in[11];
    const float* b1b = (const float*)d_in[12];
    const float* gamma1 = (const float*)d_in[13];
    const float* beta1 = (const float*)d_in[14];
    const float* W2a = (const float*)d_in[15];
    const float* b2a = (const float*)d_in[16];
    const float* W2b = (const float*)d_in[17];
    const float* b2b = (const float*)d_in[18];
    const float* gamma2 = (const float*)d_in[19];
    const float* beta2 = (const float*)d_in[20];
    float* out = (float*)d_out;

    char* ws = (char*)d_ws;
    size_t o = 0;
    auto alloc = [&](size_t bytes) -> char* {
        char* p = ws + o;
        o = (o + bytes + 255) & ~(size_t)255;
        return p;
    };
    int* off = (int*)alloc((N_NODES + 1) * sizeof(int));
    int* deg = (int*)alloc(N_NODES * sizeof(int));
    int* pos = (int*)alloc(N_NODES * sizeof(int));
    int* adj = (int*)alloc(N_EDGES * sizeof(int));
    int* part = (int*)alloc(SCAN_NB * sizeof(int));
    int* base = (int*)alloc(SCAN_NB * sizeof(int));
    float* bn1 = (float*)alloc(4 * HID * sizeof(float));
    float* bn2 = (float*)alloc(4 * NCLS * sizeof(float));
    float* stat = (float*)alloc((size_t)RB_COUNT * 4 * 256 * sizeof(float));
    unsigned short* WT1 = (unsigned short*)alloc((size_t)IN_DIM * HID * sizeof(unsigned short));
    unsigned short* WT2 = (unsigned short*)alloc((size_t)HID * HID * sizeof(unsigned short));
    unsigned short* WT3 = (unsigned short*)alloc((size_t)HID * HID * sizeof(unsigned short));
    unsigned short* Wp4 = (unsigned short*)alloc((size_t)HID * NCLS * sizeof(unsigned short));
    unsigned short* xb = (unsigned short*)alloc((size_t)N_NODES * IN_DIM * sizeof(unsigned short));
    unsigned short* A1 = (unsigned short*)alloc((size_t)N_NODES * IN_DIM * sizeof(unsigned short));
    unsigned short* B = (unsigned short*)alloc((size_t)N_NODES * HID * sizeof(unsigned short));
    unsigned short* C = (unsigned short*)alloc((size_t)N_NODES * HID * sizeof(unsigned short));

    hipMemsetAsync(deg, 0, N_NODES * sizeof(int), stream);
    hipMemsetAsync(bn1, 0, 2 * HID * sizeof(float), stream);
    hipMemsetAsync(bn2, 0, 2 * NCLS * sizeof(float), stream);

    int eb = (N_EDGES + 255) / 256;
    k_cast<<<(N_NODES * IN_DIM / 8 + 255) / 256, 256, 0, stream>>>(x, xb);
    k_deg<<<eb, 256, 0, stream>>>(dstp, deg);
    k_scan_part<<<SCAN_NB, 256, 0, stream>>>(deg, part);
    k_scan_mid<<<1, 128, 0, stream>>>(part, base, off);
    k_scan_fin<<<SCAN_NB, 256, 0, stream>>>(deg, base, off, pos);
    k_fill<<<eb, 256, 0, stream>>>(srcp, dstp, pos, adj);
    k_sortadj<<<(N_NODES + 255) / 256, 256, 0, stream>>>(off, adj);

    k_packT<<<(IN_DIM * HID) / 256, 256, 0, stream>>>(W1a, WT1, IN_DIM, HID);
    k_packT<<<(HID * HID) / 256, 256, 0, stream>>>(W1b, WT2, HID, HID);
    k_packT<<<(HID * HID) / 256, 256, 0, stream>>>(W2a, WT3, HID, HID);
    k_pack<<<(HID * NCLS) / 256, 256, 0, stream>>>(W2b, Wp4, HID, NCLS);

    int nwb = (N_NODES * 64 + 255) / 256;  // one wave per node

    // layer 1
    k_agg1<<<nwb, 256, 0, stream>>>(xb, off, adj, A1);
    k_tgemm<IN_DIM, 0, 0><<<TG_GRID, 256, 0, stream>>>(A1, WT1, b1a, B, nullptr, N_NODES);
    k_tgemm<HID, 1, 1><<<TG_GRID, 256, 0, stream>>>(B, WT2, b1b, C, stat, N_NODES);
    k_bnred<<<32, 256, 0, stream>>>(stat, bn1);
    k_bnprep<<<2, 256, 0, stream>>>(bn1, gamma1, beta1, HID, 1.0f / N_NODES);

    // layer 2
    k_aggbn2<<<dim3(nwb, 2), 256, 0, stream>>>(C, off, adj, bn1, B);
    k_tgemm<HID, 0, 0><<<TG_GRID, 256, 0, stream>>>(B, WT3, b2a, C, nullptr, N_NODES);
    k_mgemm<HID, NCLS, 1, 8, 1, 4, 1, float><<<dim3((N_NODES + 255) / 256, 1), 512, 0, stream>>>(C, Wp4, b2b, out, bn2, N_NODES);

    k_bnprep<<<1, 64, 0, stream>>>(bn2, gamma2, beta2, NCLS, 1.0f / N_NODES);
    k_softmax<<<nwb, 256, 0, stream>>>(out, bn2);
}